// Round 10
// baseline (1338.821 us; speedup 1.0000x reference)
//
#include <hip/hip_runtime.h>
#include <math.h>

#define NBLK 256
#define NTHR 512

// ---- ws layout ----
// uints [0..8191]: block b arrival flag at b*16; gen at [4096]; cnt_rt[rt] at [4352+rt*16]
// floats from 8256:
#define OFF_OBS     8256        // 8192   (cached, immutable after init barrier)
#define OFF_HS      16448       // 65536  (BYPASS domain after init)
#define OFF_PART    81984       // 524288 (BYPASS domain)
#define OFF_WTP2    606272      // 262144 (Wt_pool2 [8 hc][256 k][128 p], cached immutable)
#define OFF_WTG_E   868416      // 163840 (cached immutable)
#define OFF_WTG_D   1032256     // 163840 (cached immutable)

// LDS: pos2 0..4096 | acnt 4096..4160 | ccnt 4160..5184 | lst(u16) 5184..13376
//      hsl [256][20]f 13376..33856 | AsT [256][20]f 33856..54336
// CD reuses: AsT [320][20]f 0..25600 | red 25600..29696 | hrow 29696..30720
#define LDS_BYTES 54336

typedef float vf4 __attribute__((ext_vector_type(4)));
typedef float vf2 __attribute__((ext_vector_type(2)));

// ---------- L2-bypass (LLC-coherent) access ----------
__device__ __forceinline__ void st_bypass_f4(float* p, vf4 v) {
    asm volatile("global_store_dwordx4 %0, %1, off sc0 sc1" :: "v"(p), "v"(v) : "memory");
}
__device__ __forceinline__ void st_bypass_f2(float* p, vf2 v) {
    asm volatile("global_store_dwordx2 %0, %1, off sc0 sc1" :: "v"(p), "v"(v) : "memory");
}
__device__ __forceinline__ vf4 ld_bypass_f4(const float* p) {
    vf4 v;
    asm volatile("global_load_dwordx4 %0, %1, off sc0 sc1\n\ts_waitcnt vmcnt(0)"
                 : "=&v"(v) : "v"(p) : "memory");
    return v;
}
__device__ __forceinline__ void ld_bypass_64(const float* p, vf4& a, vf4& b, vf4& c, vf4& d) {
    asm volatile(
        "global_load_dwordx4 %0, %4, off sc0 sc1\n\t"
        "global_load_dwordx4 %1, %4, off offset:16 sc0 sc1\n\t"
        "global_load_dwordx4 %2, %4, off offset:32 sc0 sc1\n\t"
        "global_load_dwordx4 %3, %4, off offset:48 sc0 sc1\n\t"
        "s_waitcnt vmcnt(0)"
        : "=&v"(a), "=&v"(b), "=&v"(c), "=&v"(d)
        : "v"(p) : "memory");
}
__device__ __forceinline__ void ld_bypass_f4x8(const float* b, int stride, vf4* v) {
    asm volatile(
        "global_load_dwordx4 %0, %8, off sc0 sc1\n\t"
        "global_load_dwordx4 %1, %9, off sc0 sc1\n\t"
        "global_load_dwordx4 %2, %10, off sc0 sc1\n\t"
        "global_load_dwordx4 %3, %11, off sc0 sc1\n\t"
        "global_load_dwordx4 %4, %12, off sc0 sc1\n\t"
        "global_load_dwordx4 %5, %13, off sc0 sc1\n\t"
        "global_load_dwordx4 %6, %14, off sc0 sc1\n\t"
        "global_load_dwordx4 %7, %15, off sc0 sc1\n\t"
        "s_waitcnt vmcnt(0)"
        : "=&v"(v[0]), "=&v"(v[1]), "=&v"(v[2]), "=&v"(v[3]),
          "=&v"(v[4]), "=&v"(v[5]), "=&v"(v[6]), "=&v"(v[7])
        : "v"(b), "v"(b + stride), "v"(b + 2 * stride), "v"(b + 3 * stride),
          "v"(b + 4 * stride), "v"(b + 5 * stride), "v"(b + 6 * stride), "v"(b + 7 * stride)
        : "memory");
}
__device__ __forceinline__ float ld_cohere(const float* p) {
    return __hip_atomic_load(p, __ATOMIC_RELAXED, __HIP_MEMORY_SCOPE_AGENT);
}

// Fenced barrier (init only): release wbl2 before arrival, acquire inv on exit.
__device__ __forceinline__ void grid_barrier_fenced(unsigned* flags, unsigned* gen, unsigned seq) {
    __syncthreads();
    if (threadIdx.x == 0)
        __builtin_amdgcn_fence(__ATOMIC_RELEASE, "agent");
    if (blockIdx.x == 0) {
        if (threadIdx.x < 64) {
            #pragma unroll
            for (int q = 0; q < 4; q++) {
                int bb = threadIdx.x * 4 + q;
                if (bb != 0) {
                    while (__hip_atomic_load(&flags[bb * 16], __ATOMIC_RELAXED,
                                             __HIP_MEMORY_SCOPE_AGENT) != seq)
                        __builtin_amdgcn_s_sleep(1);
                }
            }
        }
        __syncthreads();
        if (threadIdx.x == 0) {
            __hip_atomic_store(gen, seq, __ATOMIC_RELAXED, __HIP_MEMORY_SCOPE_AGENT);
            __builtin_amdgcn_fence(__ATOMIC_ACQUIRE, "agent");
        }
    } else {
        if (threadIdx.x == 0) {
            __hip_atomic_store(&flags[blockIdx.x * 16], seq, __ATOMIC_RELAXED,
                               __HIP_MEMORY_SCOPE_AGENT);
            while (__hip_atomic_load(gen, __ATOMIC_RELAXED,
                                     __HIP_MEMORY_SCOPE_AGENT) != seq)
                __builtin_amdgcn_s_sleep(2);
            __builtin_amdgcn_fence(__ATOMIC_ACQUIRE, "agent");
        }
    }
    __syncthreads();
}

// Fence-free steady-state barrier: all cross-block data is in the bypass/LLC
// domain, so no cache maintenance is needed — L2-cached weights survive forever.
__device__ __forceinline__ void grid_barrier_nf(unsigned* flags, unsigned* gen, unsigned seq) {
    __syncthreads();   // drains vmcnt (bypass stores reach LLC) before flag set
    if (blockIdx.x == 0) {
        if (threadIdx.x < 64) {
            #pragma unroll
            for (int q = 0; q < 4; q++) {
                int bb = threadIdx.x * 4 + q;
                if (bb != 0) {
                    while (__hip_atomic_load(&flags[bb * 16], __ATOMIC_RELAXED,
                                             __HIP_MEMORY_SCOPE_AGENT) != seq)
                        __builtin_amdgcn_s_sleep(1);
                }
            }
        }
        __syncthreads();
        if (threadIdx.x == 0)
            __hip_atomic_store(gen, seq, __ATOMIC_RELAXED, __HIP_MEMORY_SCOPE_AGENT);
    } else {
        if (threadIdx.x == 0) {
            __hip_atomic_store(&flags[blockIdx.x * 16], seq, __ATOMIC_RELAXED,
                               __HIP_MEMORY_SCOPE_AGENT);
            while (__hip_atomic_load(gen, __ATOMIC_RELAXED,
                                     __HIP_MEMORY_SCOPE_AGENT) != seq)
                __builtin_amdgcn_s_sleep(2);
        }
    }
    __syncthreads();
}

__device__ __forceinline__ float sigm(float x) { return 1.f / (1.f + expf(-x)); }

__global__ void __launch_bounds__(NTHR, 1) social_lstm(
    const float* __restrict__ observed,
    const float* __restrict__ W_pos, const float* __restrict__ b_pos,
    const float* __restrict__ W_pool, const float* __restrict__ b_pool,
    const float* __restrict__ Wih_e, const float* __restrict__ bih_e,
    const float* __restrict__ Whh_e, const float* __restrict__ bhh_e,
    const float* __restrict__ Wih_d, const float* __restrict__ bih_d,
    const float* __restrict__ Whh_d, const float* __restrict__ bhh_d,
    const float* __restrict__ W_out, const float* __restrict__ b_out,
    float* __restrict__ out, float* __restrict__ ws, int npred)
{
    extern __shared__ char smem_raw[];
    const int t = threadIdx.x, b = blockIdx.x;
    const int gid = b * NTHR + t;

    unsigned* flags  = (unsigned*)ws;
    unsigned* gen    = flags + 4096;
    unsigned* cnt_rt = flags + 4352;
    float* obs     = ws + OFF_OBS;
    float* hs      = ws + OFF_HS;
    float* part    = ws + OFF_PART;
    float* Wt_p2   = ws + OFF_WTP2;
    float* Wt_ge   = ws + OFF_WTG_E;
    float* Wt_gd   = ws + OFF_WTG_D;
    unsigned seq = 1;

    // ================= init =================
    if (gid < 65536) hs[gid] = 0.f;
    if (gid < 512) {
        float vx[8], vy[8];
        int fin = 0;
        for (int tt = 0; tt < 8; tt++) {
            float x = observed[tt * 1024 + gid * 2];
            float y = observed[tt * 1024 + gid * 2 + 1];
            vx[tt] = x; vy[tt] = y;
            if (isfinite(x) && isfinite(y)) fin |= (1 << tt);
        }
        int firstv = -1;
        for (int tt = 7; tt >= 0; tt--) if (fin & (1 << tt)) firstv = tt;
        int last = -1;
        for (int tt = 0; tt < 8; tt++) {
            if (fin & (1 << tt)) last = tt;
            int take = (last >= 0) ? last : firstv;
            float ox = 0.f, oy = 0.f;
            if (take >= 0) { ox = vx[take]; oy = vy[take]; }
            obs[tt * 1024 + gid * 2]     = ox;
            obs[tt * 1024 + gid * 2 + 1] = oy;
        }
    }
    {   // Wt_pool2[hc][c*16+hl][p] = W_pool[p][c*128+hc*16+hl]
        #pragma unroll
        for (int q = 0; q < 2; q++) {
            int idx = gid * 2 + q;                 // 0..262143
            int p = idx & 127;
            int k2 = (idx >> 7) & 255;
            int hc2 = idx >> 15;
            int c = k2 >> 4, hl = k2 & 15;
            Wt_p2[idx] = W_pool[p * 2048 + c * 128 + hc2 * 16 + hl];
        }
    }
    for (int idx = gid; idx < 163840; idx += NBLK * NTHR) {
        int k = idx >> 9, o = idx & 511;
        float ve, vd;
        if (k < 192) { ve = Wih_e[o * 192 + k];       vd = Wih_d[o * 192 + k]; }
        else         { ve = Whh_e[o * 128 + k - 192]; vd = Whh_d[o * 128 + k - 192]; }
        Wt_ge[idx] = ve; Wt_gd[idx] = vd;
    }
    grid_barrier_fenced(flags, gen, seq++);   // flush obs/hs/weights to LLC, inv stale

    const int rt = b >> 3, hc = b & 7;
    const int R0 = rt * 16;
    float cs_reg = 0.f;       // t<256: rl=t>>4, hh=t&15
    const int nstep = 7 + npred;

    for (int s = 0; s < nstep; s++) {
        const float* posp  = (s < 7) ? (obs + (s + 1) * 1024)
                                     : ((s == 7) ? (obs + 7 * 1024) : (out + (s - 8) * 1024));
        const float* prevp = (s < 7) ? (obs + s * 1024)
                                     : ((s <= 8) ? (obs + 7 * 1024) : (out + (s - 9) * 1024));
        const float* Wt_g = (s < 7) ? Wt_ge : Wt_gd;
        const float* bihp = (s < 7) ? bih_e : bih_d;
        const float* bhhp = (s < 7) ? bhh_e : bhh_d;

        // ===== Phase AB: pooling (h-slice hc, ALL 16 cells) + soc GEMM K-chunk =====
        {
            float* pos2 = (float*)smem_raw;                             // 1024 f
            int* acnt   = (int*)(smem_raw + 4096);                      // 16
            int* ccnt   = (int*)(smem_raw + 4160);                      // 256
            unsigned short* lst = (unsigned short*)(smem_raw + 5184);   // 16*256
            float* hsl  = (float*)(smem_raw + 13376);                   // [256][20]
            float* AsT  = (float*)(smem_raw + 33856);                   // [256][20]

            if (t < 256) {
                if (s < 8) ((float4*)pos2)[t] = ((const float4*)posp)[t];
                else       ((vf4*)pos2)[t] = ld_bypass_f4(posp + t * 4);   // out rows: bypass
            }
            if (t < 16) acnt[t] = 0;
            if (t < 256) ccnt[t] = 0;
            for (int q = t; q < 256 * 20; q += NTHR) AsT[q] = -3.0e38f;
            __syncthreads();

            if (hc == 1 && s >= 7 && t < 16) {  // init out row = pos + b_out (bypass)
                int i = R0 + t;
                vf2 v;
                v.x = pos2[2 * i] + b_out[0];
                v.y = pos2[2 * i + 1] + b_out[1];
                st_bypass_f2(out + (s - 7) * 1024 + 2 * i, v);
            }
            {   // pair eval: agent a = t>>5, all 16 cells
                int a = t >> 5, i = R0 + a;
                float pix = pos2[2 * i], piy = pos2[2 * i + 1];
                for (int jj = 0; jj < 16; jj++) {
                    int j = (t & 31) + jj * 32;
                    float dx = pos2[2 * j]     - pix;
                    float dy = pos2[2 * j + 1] - piy;
                    if (j != i && fabsf(dx) <= 1.0f && fabsf(dy) <= 1.0f) {
                        int gx = (int)floorf((dx + 1.0f) * 2.0f); gx = gx < 0 ? 0 : (gx > 3 ? 3 : gx);
                        int gy = (int)floorf((dy + 1.0f) * 2.0f); gy = gy < 0 ? 0 : (gy > 3 ? 3 : gy);
                        int cell = gx * 4 + gy;
                        atomicAdd(&ccnt[a * 16 + cell], 1);
                        int slot = atomicAdd(&acnt[a], 1);
                        if (slot < 256) lst[a * 256 + slot] = (unsigned short)((cell << 9) | j);
                    }
                }
            }
            __syncthreads();
            // two-pass gather: 256 hs rows at a time (hsl = 20 KB LDS)
            for (int half = 0; half < 2; half++) {
                if (t < 256) {   // load hs[:, hc*16..+15] slice: one 64B line per agent
                    int j = half * 256 + t;
                    vf4 a0, a1, a2, a3;
                    ld_bypass_64(hs + j * 128 + hc * 16, a0, a1, a2, a3);
                    float* d = hsl + t * 20;
                    *(vf4*)(d)      = a0;
                    *(vf4*)(d + 4)  = a1;
                    *(vf4*)(d + 8)  = a2;
                    *(vf4*)(d + 12) = a3;
                }
                __syncthreads();
                if (t < 256) {   // max-accumulate directly into AsT[k=cell*16+hl][a]
                    int a = t >> 4, hl = t & 15;
                    int len = acnt[a]; if (len > 256) len = 256;
                    for (int e = 0; e < len; e++) {
                        int pk = lst[a * 256 + e];
                        int j = pk & 511;
                        if ((j >> 8) == half) {
                            float v = hsl[(j & 255) * 20 + hl];
                            float* cp = &AsT[((pk >> 9) * 16 + hl) * 20 + a];
                            *cp = fmaxf(*cp, v);
                        }
                    }
                }
                __syncthreads();
            }
            if (t < 256) {   // fixup: empty cells -> 0
                int k = t, c = k >> 4;
                #pragma unroll
                for (int a = 0; a < 16; a++) {
                    float v = AsT[k * 20 + a];
                    AsT[k * 20 + a] = (ccnt[a * 16 + c] > 0) ? v : 0.f;
                }
            }
            __syncthreads();
            {   // soc GEMM: 16r x 128o x K256; tile 4x8; in-wave 8-way ksplit
                int og = (t & 7) | (((t >> 6) & 1) << 3);
                int ks = (t >> 3) & 7;
                int rowg = t >> 7;
                float acc[4][8];
                #pragma unroll
                for (int r = 0; r < 4; r++)
                    #pragma unroll
                    for (int o = 0; o < 8; o++) acc[r][o] = 0.f;
                const float4* W4 = (const float4*)Wt_p2;   // [8][256][128], L2-resident forever
                #pragma unroll 4
                for (int kk = 0; kk < 32; kk++) {
                    int kl = ks * 32 + kk;
                    float4 a4 = *(const float4*)&AsT[kl * 20 + rowg * 4];
                    float4 w0 = W4[(hc * 256 + kl) * 32 + og * 2];
                    float4 w1 = W4[(hc * 256 + kl) * 32 + og * 2 + 1];
                    float ar[4] = {a4.x, a4.y, a4.z, a4.w};
                    float wo[8] = {w0.x, w0.y, w0.z, w0.w, w1.x, w1.y, w1.z, w1.w};
                    #pragma unroll
                    for (int r = 0; r < 4; r++)
                        #pragma unroll
                        for (int o = 0; o < 8; o++)
                            acc[r][o] = fmaf(ar[r], wo[o], acc[r][o]);
                }
                #pragma unroll
                for (int r = 0; r < 4; r++)
                    #pragma unroll
                    for (int o = 0; o < 8; o++) {
                        acc[r][o] += __shfl_xor(acc[r][o], 8);
                        acc[r][o] += __shfl_xor(acc[r][o], 16);
                        acc[r][o] += __shfl_xor(acc[r][o], 32);
                    }
                if ((t & 56) == 0) {
                    #pragma unroll
                    for (int r = 0; r < 4; r++) {
                        int row = R0 + rowg * 4 + r;
                        float* pp = part + hc * 65536 + row * 128 + og * 8;
                        vf4 lo, hi;
                        lo.x = acc[r][0]; lo.y = acc[r][1]; lo.z = acc[r][2]; lo.w = acc[r][3];
                        hi.x = acc[r][4]; hi.y = acc[r][5]; hi.z = acc[r][6]; hi.w = acc[r][7];
                        st_bypass_f4(pp,     lo);
                        st_bypass_f4(pp + 4, hi);
                    }
                }
            }
        }

        // ---- local 8-producer sync per row-group (no fences) ----
        __syncthreads();                 // drains bypass stores
        if (t == 0) {
            __hip_atomic_fetch_add(&cnt_rt[rt * 16], 1u, __ATOMIC_RELAXED, __HIP_MEMORY_SCOPE_AGENT);
            unsigned tgt = 8u * (unsigned)(s + 1);
            while (__hip_atomic_load(&cnt_rt[rt * 16], __ATOMIC_RELAXED,
                                     __HIP_MEMORY_SCOPE_AGENT) != tgt)
                __builtin_amdgcn_s_sleep(1);
        }
        __syncthreads();

        // ===== Phase CD: gates GEMM (h-aligned) + pointwise LSTM =====
        {
            float* AsT  = (float*)smem_raw;                 // [320][20]
            float* red  = (float*)(smem_raw + 25600);       // [16][64]
            float* hrow = (float*)(smem_raw + 29696);       // [16][16]
            {   // stage emb rows (k 0..63), computed locally; pos via LLC loads
                int r = t >> 5, e2 = (t & 31) * 2;
                int i2 = 2 * (R0 + r);
                float vx = ld_cohere(posp + i2)     - ld_cohere(prevp + i2);
                float vy = ld_cohere(posp + i2 + 1) - ld_cohere(prevp + i2 + 1);
                float e0 = fmaxf(W_pos[e2 * 2]     * vx + W_pos[e2 * 2 + 1] * vy + b_pos[e2],     0.f);
                float e1 = fmaxf(W_pos[e2 * 2 + 2] * vx + W_pos[e2 * 2 + 3] * vy + b_pos[e2 + 1], 0.f);
                AsT[(e2 + 0) * 20 + r] = e0;
                AsT[(e2 + 1) * 20 + r] = e1;
            }
            {   // stage soc rows (k 64..191): bypass part reduce + bias + relu
                int r = t >> 5, p4 = (t & 31) * 4;
                vf4 pv[8];
                ld_bypass_f4x8(part + (R0 + r) * 128 + p4, 65536, pv);
                float sv[4] = {0.f, 0.f, 0.f, 0.f};
                #pragma unroll
                for (int kc2 = 0; kc2 < 8; kc2++) {
                    sv[0] += pv[kc2].x; sv[1] += pv[kc2].y;
                    sv[2] += pv[kc2].z; sv[3] += pv[kc2].w;
                }
                #pragma unroll
                for (int u = 0; u < 4; u++)
                    AsT[(64 + p4 + u) * 20 + r] = fmaxf(sv[u] + b_pool[p4 + u], 0.f);
            }
            {   // stage hs rows (k 192..319): bypass
                int r = t >> 5, h4 = (t & 31) * 4;
                vf4 v = ld_bypass_f4(hs + (R0 + r) * 128 + h4);
                AsT[(192 + h4 + 0) * 20 + r] = v.x;
                AsT[(192 + h4 + 1) * 20 + r] = v.y;
                AsT[(192 + h4 + 2) * 20 + r] = v.z;
                AsT[(192 + h4 + 3) * 20 + r] = v.w;
            }
            __syncthreads();
            {   // gates GEMM: 16r x 64o x K320; tile 4x4; in-wave 8-way ksplit
                int og = (t & 7) | (((t >> 6) & 1) << 3);
                int ks = (t >> 3) & 7;
                int rowg = t >> 7;
                int col4 = (og >> 2) * 32 + hc * 4 + (og & 3);
                float acc[4][4];
                #pragma unroll
                for (int r = 0; r < 4; r++)
                    #pragma unroll
                    for (int o = 0; o < 4; o++) acc[r][o] = 0.f;
                const float4* Wg4 = (const float4*)Wt_g;    // L2-resident (never invalidated)
                #pragma unroll 4
                for (int kk = 0; kk < 40; kk++) {
                    int k = ks * 40 + kk;
                    float4 a4 = *(const float4*)&AsT[k * 20 + rowg * 4];
                    float4 w  = Wg4[k * 128 + col4];
                    float ar[4] = {a4.x, a4.y, a4.z, a4.w};
                    float wo[4] = {w.x, w.y, w.z, w.w};
                    #pragma unroll
                    for (int r = 0; r < 4; r++)
                        #pragma unroll
                        for (int o = 0; o < 4; o++)
                            acc[r][o] = fmaf(ar[r], wo[o], acc[r][o]);
                }
                #pragma unroll
                for (int r = 0; r < 4; r++)
                    #pragma unroll
                    for (int o = 0; o < 4; o++) {
                        acc[r][o] += __shfl_xor(acc[r][o], 8);
                        acc[r][o] += __shfl_xor(acc[r][o], 16);
                        acc[r][o] += __shfl_xor(acc[r][o], 32);
                    }
                if ((t & 56) == 0) {
                    #pragma unroll
                    for (int r = 0; r < 4; r++)
                        *(float4*)&red[(rowg * 4 + r) * 64 + og * 4] =
                            make_float4(acc[r][0], acc[r][1], acc[r][2], acc[r][3]);
                }
            }
            __syncthreads();
            if (t < 256) {   // pointwise LSTM
                int rl = t >> 4, hh = t & 15;
                float g4[4];
                #pragma unroll
                for (int q = 0; q < 4; q++) {
                    int colq = q * 128 + hc * 16 + hh;
                    g4[q] = red[rl * 64 + q * 16 + hh] + bihp[colq] + bhhp[colq];
                }
                float si = sigm(g4[0]);
                float sf = sigm(g4[1]);
                float so = sigm(g4[3]);
                float c2 = sf * cs_reg + si * tanhf(g4[2]);
                float h2 = so * tanhf(c2);
                cs_reg = c2;
                hrow[rl * 16 + hh] = h2;
                if (s >= 7) {
                    int i = R0 + rl, h = hc * 16 + hh;
                    float v0 = W_out[h] * h2;
                    float v1 = W_out[128 + h] * h2;
                    v0 += __shfl_down(v0, 8); v0 += __shfl_down(v0, 4);
                    v0 += __shfl_down(v0, 2); v0 += __shfl_down(v0, 1);
                    v1 += __shfl_down(v1, 8); v1 += __shfl_down(v1, 4);
                    v1 += __shfl_down(v1, 2); v1 += __shfl_down(v1, 1);
                    if (hh == 0) {
                        atomicAdd(&out[(s - 7) * 1024 + 2 * i],     v0);
                        atomicAdd(&out[(s - 7) * 1024 + 2 * i + 1], v1);
                    }
                }
            }
            __syncthreads();
            if (t < 64) {   // coalesced bypass hs writeback: 64B per agent slice
                int rl = t >> 2, q = t & 3;
                vf4 v;
                v.x = hrow[rl * 16 + q * 4 + 0];
                v.y = hrow[rl * 16 + q * 4 + 1];
                v.z = hrow[rl * 16 + q * 4 + 2];
                v.w = hrow[rl * 16 + q * 4 + 3];
                st_bypass_f4(hs + (R0 + rl) * 128 + hc * 16 + q * 4, v);
            }
        }
        grid_barrier_nf(flags, gen, seq++);   // fence-free: no L2 invalidation
    }
}

extern "C" void kernel_launch(void* const* d_in, const int* in_sizes, int n_in,
                              void* d_out, int out_size, void* d_ws, size_t ws_size,
                              hipStream_t stream) {
    const float* observed = (const float*)d_in[0];
    const float* W_pos    = (const float*)d_in[1];
    const float* b_pos    = (const float*)d_in[2];
    const float* W_pool   = (const float*)d_in[3];
    const float* b_pool   = (const float*)d_in[4];
    const float* Wih_e    = (const float*)d_in[5];
    const float* bih_e    = (const float*)d_in[6];
    const float* Whh_e    = (const float*)d_in[7];
    const float* bhh_e    = (const float*)d_in[8];
    const float* Wih_d    = (const float*)d_in[9];
    const float* bih_d    = (const float*)d_in[10];
    const float* Whh_d    = (const float*)d_in[11];
    const float* bhh_d    = (const float*)d_in[12];
    const float* W_out    = (const float*)d_in[13];
    const float* b_out    = (const float*)d_in[14];
    float* outp = (float*)d_out;
    float* wsp  = (float*)d_ws;
    int npred = out_size / 1024;

    hipMemsetAsync(d_ws, 0, 33024, stream);   // flags + gen + cnt_rt

    social_lstm<<<NBLK, NTHR, LDS_BYTES, stream>>>(
        observed, W_pos, b_pos, W_pool, b_pool,
        Wih_e, bih_e, Whh_e, bhh_e,
        Wih_d, bih_d, Whh_d, bhh_d,
        W_out, b_out, outp, wsp, npred);
}

// Round 11
// 690.590 us; speedup vs baseline: 1.9387x; 1.9387x over previous
//
#include <hip/hip_runtime.h>
#include <math.h>

#define NBLK 256
#define NTHR 512

// ---- ws layout ----
// uints [0..8191]: block b arrival flag at b*16; gen at [4096]; cnt_rt[rt] at [4352+rt*16]
// floats from 8256:
#define OFF_OBS     8256        // 8192   (cached, immutable after init barrier)
#define OFF_HS      16448       // 65536  (BYPASS/LLC domain after init)
#define OFF_PART    81984       // 524288 (BYPASS domain)
#define OFF_WTPOOL  606272      // 262144 (Wt_pool [2048][128], cached immutable)
#define OFF_WTG_E   868416      // 163840 (cached immutable)
#define OFF_WTG_D   1032256     // 163840 (cached immutable)

#define LDS_BYTES 30848

typedef float vf4 __attribute__((ext_vector_type(4)));
typedef float vf2 __attribute__((ext_vector_type(2)));

// ---------- L2-bypass (LLC-coherent) access ----------
__device__ __forceinline__ void st_bypass_f4(float* p, vf4 v) {
    asm volatile("global_store_dwordx4 %0, %1, off sc0 sc1" :: "v"(p), "v"(v) : "memory");
}
__device__ __forceinline__ void st_bypass_f2(float* p, vf2 v) {
    asm volatile("global_store_dwordx2 %0, %1, off sc0 sc1" :: "v"(p), "v"(v) : "memory");
}
__device__ __forceinline__ vf4 ld_bypass_f4(const float* p) {
    vf4 v;
    asm volatile("global_load_dwordx4 %0, %1, off sc0 sc1\n\ts_waitcnt vmcnt(0)"
                 : "=&v"(v) : "v"(p) : "memory");
    return v;
}
__device__ __forceinline__ void ld_bypass_f4x8(const float* b, int stride, vf4* v) {
    asm volatile(
        "global_load_dwordx4 %0, %8, off sc0 sc1\n\t"
        "global_load_dwordx4 %1, %9, off sc0 sc1\n\t"
        "global_load_dwordx4 %2, %10, off sc0 sc1\n\t"
        "global_load_dwordx4 %3, %11, off sc0 sc1\n\t"
        "global_load_dwordx4 %4, %12, off sc0 sc1\n\t"
        "global_load_dwordx4 %5, %13, off sc0 sc1\n\t"
        "global_load_dwordx4 %6, %14, off sc0 sc1\n\t"
        "global_load_dwordx4 %7, %15, off sc0 sc1\n\t"
        "s_waitcnt vmcnt(0)"
        : "=&v"(v[0]), "=&v"(v[1]), "=&v"(v[2]), "=&v"(v[3]),
          "=&v"(v[4]), "=&v"(v[5]), "=&v"(v[6]), "=&v"(v[7])
        : "v"(b), "v"(b + stride), "v"(b + 2 * stride), "v"(b + 3 * stride),
          "v"(b + 4 * stride), "v"(b + 5 * stride), "v"(b + 6 * stride), "v"(b + 7 * stride)
        : "memory");
}
// 8-byte LLC load via relaxed agent atomic: compiler schedules/pipelines these
// (no inline-asm waitcnt per load) -> good MLP in the gather loop.
__device__ __forceinline__ vf2 ld_llc_f2(const float* p) {
    union { unsigned long long u; vf2 f; } cv;
    cv.u = __hip_atomic_load((const unsigned long long*)p, __ATOMIC_RELAXED,
                             __HIP_MEMORY_SCOPE_AGENT);
    return cv.f;
}
__device__ __forceinline__ float ld_cohere(const float* p) {
    return __hip_atomic_load(p, __ATOMIC_RELAXED, __HIP_MEMORY_SCOPE_AGENT);
}

// Fenced barrier (init only): release wbl2 before arrival, acquire inv on exit.
__device__ __forceinline__ void grid_barrier_fenced(unsigned* flags, unsigned* gen, unsigned seq) {
    __syncthreads();
    if (threadIdx.x == 0)
        __builtin_amdgcn_fence(__ATOMIC_RELEASE, "agent");
    if (blockIdx.x == 0) {
        if (threadIdx.x < 64) {
            #pragma unroll
            for (int q = 0; q < 4; q++) {
                int bb = threadIdx.x * 4 + q;
                if (bb != 0) {
                    while (__hip_atomic_load(&flags[bb * 16], __ATOMIC_RELAXED,
                                             __HIP_MEMORY_SCOPE_AGENT) != seq)
                        __builtin_amdgcn_s_sleep(1);
                }
            }
        }
        __syncthreads();
        if (threadIdx.x == 0) {
            __hip_atomic_store(gen, seq, __ATOMIC_RELAXED, __HIP_MEMORY_SCOPE_AGENT);
            __builtin_amdgcn_fence(__ATOMIC_ACQUIRE, "agent");
        }
    } else {
        if (threadIdx.x == 0) {
            __hip_atomic_store(&flags[blockIdx.x * 16], seq, __ATOMIC_RELAXED,
                               __HIP_MEMORY_SCOPE_AGENT);
            while (__hip_atomic_load(gen, __ATOMIC_RELAXED,
                                     __HIP_MEMORY_SCOPE_AGENT) != seq)
                __builtin_amdgcn_s_sleep(2);
            __builtin_amdgcn_fence(__ATOMIC_ACQUIRE, "agent");
        }
    }
    __syncthreads();
}

// Fence-free steady-state barrier: ALL cross-block mutable data (hs, part, out)
// is in the bypass/LLC domain, so no cache maintenance is needed — the cached
// weights stay L2-resident for the whole kernel (no per-step refetch).
__device__ __forceinline__ void grid_barrier_nf(unsigned* flags, unsigned* gen, unsigned seq) {
    __syncthreads();   // per-wave vmcnt drain: bypass stores are at LLC before flag set
    if (blockIdx.x == 0) {
        if (threadIdx.x < 64) {
            #pragma unroll
            for (int q = 0; q < 4; q++) {
                int bb = threadIdx.x * 4 + q;
                if (bb != 0) {
                    while (__hip_atomic_load(&flags[bb * 16], __ATOMIC_RELAXED,
                                             __HIP_MEMORY_SCOPE_AGENT) != seq)
                        __builtin_amdgcn_s_sleep(1);
                }
            }
        }
        __syncthreads();
        if (threadIdx.x == 0)
            __hip_atomic_store(gen, seq, __ATOMIC_RELAXED, __HIP_MEMORY_SCOPE_AGENT);
    } else {
        if (threadIdx.x == 0) {
            __hip_atomic_store(&flags[blockIdx.x * 16], seq, __ATOMIC_RELAXED,
                               __HIP_MEMORY_SCOPE_AGENT);
            while (__hip_atomic_load(gen, __ATOMIC_RELAXED,
                                     __HIP_MEMORY_SCOPE_AGENT) != seq)
                __builtin_amdgcn_s_sleep(2);
        }
    }
    __syncthreads();
}

__device__ __forceinline__ float sigm(float x) { return 1.f / (1.f + expf(-x)); }

__global__ void __launch_bounds__(NTHR, 1) social_lstm(
    const float* __restrict__ observed,
    const float* __restrict__ W_pos, const float* __restrict__ b_pos,
    const float* __restrict__ W_pool, const float* __restrict__ b_pool,
    const float* __restrict__ Wih_e, const float* __restrict__ bih_e,
    const float* __restrict__ Whh_e, const float* __restrict__ bhh_e,
    const float* __restrict__ Wih_d, const float* __restrict__ bih_d,
    const float* __restrict__ Whh_d, const float* __restrict__ bhh_d,
    const float* __restrict__ W_out, const float* __restrict__ b_out,
    float* __restrict__ out, float* __restrict__ ws, int npred)
{
    extern __shared__ char smem_raw[];
    const int t = threadIdx.x, b = blockIdx.x;
    const int gid = b * NTHR + t;

    unsigned* flags  = (unsigned*)ws;
    unsigned* gen    = flags + 4096;
    unsigned* cnt_rt = flags + 4352;
    float* obs     = ws + OFF_OBS;
    float* hs      = ws + OFF_HS;
    float* part    = ws + OFF_PART;
    float* Wt_pool = ws + OFF_WTPOOL;
    float* Wt_ge   = ws + OFF_WTG_E;
    float* Wt_gd   = ws + OFF_WTG_D;
    unsigned seq = 1;

    // ================= init =================
    if (gid < 65536) hs[gid] = 0.f;
    if (gid < 512) {
        float vx[8], vy[8];
        int fin = 0;
        for (int tt = 0; tt < 8; tt++) {
            float x = observed[tt * 1024 + gid * 2];
            float y = observed[tt * 1024 + gid * 2 + 1];
            vx[tt] = x; vy[tt] = y;
            if (isfinite(x) && isfinite(y)) fin |= (1 << tt);
        }
        int firstv = -1;
        for (int tt = 7; tt >= 0; tt--) if (fin & (1 << tt)) firstv = tt;
        int last = -1;
        for (int tt = 0; tt < 8; tt++) {
            if (fin & (1 << tt)) last = tt;
            int take = (last >= 0) ? last : firstv;
            float ox = 0.f, oy = 0.f;
            if (take >= 0) { ox = vx[take]; oy = vy[take]; }
            obs[tt * 1024 + gid * 2]     = ox;
            obs[tt * 1024 + gid * 2 + 1] = oy;
        }
    }
    if (gid < 65536) {   // Wt_pool[k][p] = W_pool[p][k]
        int p = gid >> 9, k4 = gid & 511;
        float4 v = *(const float4*)(W_pool + p * 2048 + k4 * 4);
        float* dst = Wt_pool + (k4 * 4) * 128 + p;
        dst[0] = v.x; dst[128] = v.y; dst[256] = v.z; dst[384] = v.w;
    }
    for (int idx = gid; idx < 163840; idx += NBLK * NTHR) {
        int k = idx >> 9, o = idx & 511;
        float ve, vd;
        if (k < 192) { ve = Wih_e[o * 192 + k];       vd = Wih_d[o * 192 + k]; }
        else         { ve = Whh_e[o * 128 + k - 192]; vd = Whh_d[o * 128 + k - 192]; }
        Wt_ge[idx] = ve; Wt_gd[idx] = vd;
    }
    grid_barrier_fenced(flags, gen, seq++);   // one-time flush/inv: weights+obs+hs at LLC

    const int rt = b >> 3, kc = b & 7, hc = kc;
    const int R0 = rt * 16;
    float cs_reg = 0.f;       // t<256: rl=t>>4, hh=t&15
    const int nstep = 7 + npred;

    for (int s = 0; s < nstep; s++) {
        const float* posp  = (s < 7) ? (obs + (s + 1) * 1024)
                                     : ((s == 7) ? (obs + 7 * 1024) : (out + (s - 8) * 1024));
        const float* prevp = (s < 7) ? (obs + s * 1024)
                                     : ((s <= 8) ? (obs + 7 * 1024) : (out + (s - 9) * 1024));
        const float* Wt_g = (s < 7) ? Wt_ge : Wt_gd;
        const float* bihp = (s < 7) ? bih_e : bih_d;
        const float* bhhp = (s < 7) ? bhh_e : bhh_d;

        // ===== Phase AB: pooling (2 cells) + soc GEMM K-chunk =====
        {
            float* pos2 = (float*)smem_raw;                           // 1024 f
            int* cnt    = (int*)(smem_raw + 4096);                    // 32 i
            unsigned short* lst = (unsigned short*)(smem_raw + 4224); // 32*96 us
            float* AsT  = (float*)(smem_raw + 10368);                 // 256*20 f

            if (t < 256) {
                if (s < 8) ((float4*)pos2)[t] = ((const float4*)posp)[t];   // obs: cached
                else       ((vf4*)pos2)[t] = ld_bypass_f4(posp + t * 4);    // out: LLC
            }
            if (t < 32) cnt[t] = 0;
            __syncthreads();

            if (kc == 1 && s >= 7 && t < 16) {  // init out row = pos + b_out (bypass)
                int i = R0 + t;
                vf2 v;
                v.x = pos2[2 * i] + b_out[0];
                v.y = pos2[2 * i + 1] + b_out[1];
                st_bypass_f2(out + (s - 7) * 1024 + 2 * i, v);
            }
            {   // pair eval: agent a = t>>5, 32 threads/agent
                int a = t >> 5, i = R0 + a;
                float pix = pos2[2 * i], piy = pos2[2 * i + 1];
                int c0 = kc * 2;
                for (int jj = 0; jj < 16; jj++) {
                    int j = (t & 31) + jj * 32;
                    float dx = pos2[2 * j]     - pix;
                    float dy = pos2[2 * j + 1] - piy;
                    if (j != i && fabsf(dx) <= 1.0f && fabsf(dy) <= 1.0f) {
                        int gx = (int)floorf((dx + 1.0f) * 2.0f); gx = gx < 0 ? 0 : (gx > 3 ? 3 : gx);
                        int gy = (int)floorf((dy + 1.0f) * 2.0f); gy = gy < 0 ? 0 : (gy > 3 ? 3 : gy);
                        int cc = gx * 4 + gy - c0;
                        if (cc == 0 || cc == 1) {
                            int slot = atomicAdd(&cnt[a * 2 + cc], 1);
                            if (slot < 96) lst[(a * 2 + cc) * 96 + slot] = (unsigned short)j;
                        }
                    }
                }
            }
            __syncthreads();
            {   // cell max -> AsT[k][agent]: thread = (a, cc, hq); hs via LLC loads
                int a = t >> 5, cc = (t >> 4) & 1, hq = t & 15;
                int len = cnt[a * 2 + cc]; if (len > 96) len = 96;
                float m[8];
                #pragma unroll
                for (int u = 0; u < 8; u++) m[u] = -3.0e38f;
                for (int e = 0; e < len; e++) {
                    int j = lst[(a * 2 + cc) * 96 + e];
                    const float* hr = hs + j * 128 + hq * 8;
                    vf2 p0 = ld_llc_f2(hr);
                    vf2 p1 = ld_llc_f2(hr + 2);
                    vf2 p2 = ld_llc_f2(hr + 4);
                    vf2 p3 = ld_llc_f2(hr + 6);
                    m[0] = fmaxf(m[0], p0.x); m[1] = fmaxf(m[1], p0.y);
                    m[2] = fmaxf(m[2], p1.x); m[3] = fmaxf(m[3], p1.y);
                    m[4] = fmaxf(m[4], p2.x); m[5] = fmaxf(m[5], p2.y);
                    m[6] = fmaxf(m[6], p3.x); m[7] = fmaxf(m[7], p3.y);
                }
                #pragma unroll
                for (int u = 0; u < 8; u++)
                    AsT[(cc * 128 + hq * 8 + u) * 20 + a] = (len > 0) ? m[u] : 0.f;
            }
            __syncthreads();
            {   // soc GEMM: 16r x 128o x K256; tile 4x8; in-wave 8-way ksplit
                int og = (t & 7) | (((t >> 6) & 1) << 3);
                int ks = (t >> 3) & 7;
                int rowg = t >> 7;
                float acc[4][8];
                #pragma unroll
                for (int r = 0; r < 4; r++)
                    #pragma unroll
                    for (int o = 0; o < 8; o++) acc[r][o] = 0.f;
                const float4* W4 = (const float4*)Wt_pool;   // L2-resident all 19 steps
                int kb = kc * 256 + ks * 32;
                #pragma unroll 4
                for (int kk = 0; kk < 32; kk++) {
                    int kl = ks * 32 + kk;
                    float4 a4 = *(const float4*)&AsT[kl * 20 + rowg * 4];
                    float4 w0 = W4[(kb + kk) * 32 + og * 2];
                    float4 w1 = W4[(kb + kk) * 32 + og * 2 + 1];
                    float ar[4] = {a4.x, a4.y, a4.z, a4.w};
                    float wo[8] = {w0.x, w0.y, w0.z, w0.w, w1.x, w1.y, w1.z, w1.w};
                    #pragma unroll
                    for (int r = 0; r < 4; r++)
                        #pragma unroll
                        for (int o = 0; o < 8; o++)
                            acc[r][o] = fmaf(ar[r], wo[o], acc[r][o]);
                }
                #pragma unroll
                for (int r = 0; r < 4; r++)
                    #pragma unroll
                    for (int o = 0; o < 8; o++) {
                        acc[r][o] += __shfl_xor(acc[r][o], 8);
                        acc[r][o] += __shfl_xor(acc[r][o], 16);
                        acc[r][o] += __shfl_xor(acc[r][o], 32);
                    }
                if ((t & 56) == 0) {
                    #pragma unroll
                    for (int r = 0; r < 4; r++) {
                        int row = R0 + rowg * 4 + r;
                        float* pp = part + kc * 65536 + row * 128 + og * 8;
                        vf4 lo, hi;
                        lo.x = acc[r][0]; lo.y = acc[r][1]; lo.z = acc[r][2]; lo.w = acc[r][3];
                        hi.x = acc[r][4]; hi.y = acc[r][5]; hi.z = acc[r][6]; hi.w = acc[r][7];
                        st_bypass_f4(pp,     lo);
                        st_bypass_f4(pp + 4, hi);
                    }
                }
            }
        }

        // ---- local 8-producer sync per row-group (no fences) ----
        __syncthreads();                 // drains bypass stores
        if (t == 0) {
            __hip_atomic_fetch_add(&cnt_rt[rt * 16], 1u, __ATOMIC_RELAXED, __HIP_MEMORY_SCOPE_AGENT);
            unsigned tgt = 8u * (unsigned)(s + 1);
            while (__hip_atomic_load(&cnt_rt[rt * 16], __ATOMIC_RELAXED,
                                     __HIP_MEMORY_SCOPE_AGENT) != tgt)
                __builtin_amdgcn_s_sleep(1);
        }
        __syncthreads();

        // ===== Phase CD: gates GEMM (h-aligned) + pointwise LSTM =====
        {
            float* AsT  = (float*)smem_raw;                 // [320][20]
            float* red  = (float*)(smem_raw + 25600);       // [16][64]
            float* hrow = (float*)(smem_raw + 29696);       // [16][16]
            {   // stage emb rows (k 0..63), computed locally; pos via LLC loads
                int r = t >> 5, e2 = (t & 31) * 2;
                int i2 = 2 * (R0 + r);
                float vx = ld_cohere(posp + i2)     - ld_cohere(prevp + i2);
                float vy = ld_cohere(posp + i2 + 1) - ld_cohere(prevp + i2 + 1);
                float e0 = fmaxf(W_pos[e2 * 2]     * vx + W_pos[e2 * 2 + 1] * vy + b_pos[e2],     0.f);
                float e1 = fmaxf(W_pos[e2 * 2 + 2] * vx + W_pos[e2 * 2 + 3] * vy + b_pos[e2 + 1], 0.f);
                AsT[(e2 + 0) * 20 + r] = e0;
                AsT[(e2 + 1) * 20 + r] = e1;
            }
            {   // stage soc rows (k 64..191): bypass part reduce + bias + relu
                int r = t >> 5, p4 = (t & 31) * 4;
                vf4 pv[8];
                ld_bypass_f4x8(part + (R0 + r) * 128 + p4, 65536, pv);
                float sv[4] = {0.f, 0.f, 0.f, 0.f};
                #pragma unroll
                for (int kc2 = 0; kc2 < 8; kc2++) {
                    sv[0] += pv[kc2].x; sv[1] += pv[kc2].y;
                    sv[2] += pv[kc2].z; sv[3] += pv[kc2].w;
                }
                #pragma unroll
                for (int u = 0; u < 4; u++)
                    AsT[(64 + p4 + u) * 20 + r] = fmaxf(sv[u] + b_pool[p4 + u], 0.f);
            }
            {   // stage hs rows (k 192..319): bypass
                int r = t >> 5, h4 = (t & 31) * 4;
                vf4 v = ld_bypass_f4(hs + (R0 + r) * 128 + h4);
                AsT[(192 + h4 + 0) * 20 + r] = v.x;
                AsT[(192 + h4 + 1) * 20 + r] = v.y;
                AsT[(192 + h4 + 2) * 20 + r] = v.z;
                AsT[(192 + h4 + 3) * 20 + r] = v.w;
            }
            __syncthreads();
            {   // gates GEMM: 16r x 64o x K320; tile 4x4; in-wave 8-way ksplit
                int og = (t & 7) | (((t >> 6) & 1) << 3);
                int ks = (t >> 3) & 7;
                int rowg = t >> 7;
                int col4 = (og >> 2) * 32 + hc * 4 + (og & 3);
                float acc[4][4];
                #pragma unroll
                for (int r = 0; r < 4; r++)
                    #pragma unroll
                    for (int o = 0; o < 4; o++) acc[r][o] = 0.f;
                const float4* Wg4 = (const float4*)Wt_g;    // L2-resident (never invalidated)
                #pragma unroll 4
                for (int kk = 0; kk < 40; kk++) {
                    int k = ks * 40 + kk;
                    float4 a4 = *(const float4*)&AsT[k * 20 + rowg * 4];
                    float4 w  = Wg4[k * 128 + col4];
                    float ar[4] = {a4.x, a4.y, a4.z, a4.w};
                    float wo[4] = {w.x, w.y, w.z, w.w};
                    #pragma unroll
                    for (int r = 0; r < 4; r++)
                        #pragma unroll
                        for (int o = 0; o < 4; o++)
                            acc[r][o] = fmaf(ar[r], wo[o], acc[r][o]);
                }
                #pragma unroll
                for (int r = 0; r < 4; r++)
                    #pragma unroll
                    for (int o = 0; o < 4; o++) {
                        acc[r][o] += __shfl_xor(acc[r][o], 8);
                        acc[r][o] += __shfl_xor(acc[r][o], 16);
                        acc[r][o] += __shfl_xor(acc[r][o], 32);
                    }
                if ((t & 56) == 0) {
                    #pragma unroll
                    for (int r = 0; r < 4; r++)
                        *(float4*)&red[(rowg * 4 + r) * 64 + og * 4] =
                            make_float4(acc[r][0], acc[r][1], acc[r][2], acc[r][3]);
                }
            }
            __syncthreads();
            if (t < 256) {   // pointwise LSTM
                int rl = t >> 4, hh = t & 15;
                float g4[4];
                #pragma unroll
                for (int q = 0; q < 4; q++) {
                    int colq = q * 128 + hc * 16 + hh;
                    g4[q] = red[rl * 64 + q * 16 + hh] + bihp[colq] + bhhp[colq];
                }
                float si = sigm(g4[0]);
                float sf = sigm(g4[1]);
                float so = sigm(g4[3]);
                float c2 = sf * cs_reg + si * tanhf(g4[2]);
                float h2 = so * tanhf(c2);
                cs_reg = c2;
                hrow[rl * 16 + hh] = h2;
                if (s >= 7) {
                    int i = R0 + rl, h = hc * 16 + hh;
                    float v0 = W_out[h] * h2;
                    float v1 = W_out[128 + h] * h2;
                    v0 += __shfl_down(v0, 8); v0 += __shfl_down(v0, 4);
                    v0 += __shfl_down(v0, 2); v0 += __shfl_down(v0, 1);
                    v1 += __shfl_down(v1, 8); v1 += __shfl_down(v1, 4);
                    v1 += __shfl_down(v1, 2); v1 += __shfl_down(v1, 1);
                    if (hh == 0) {
                        atomicAdd(&out[(s - 7) * 1024 + 2 * i],     v0);
                        atomicAdd(&out[(s - 7) * 1024 + 2 * i + 1], v1);
                    }
                }
            }
            __syncthreads();
            if (t < 64) {   // coalesced bypass hs writeback: 64B per agent h-slice
                int rl = t >> 2, q = t & 3;
                vf4 v;
                v.x = hrow[rl * 16 + q * 4 + 0];
                v.y = hrow[rl * 16 + q * 4 + 1];
                v.z = hrow[rl * 16 + q * 4 + 2];
                v.w = hrow[rl * 16 + q * 4 + 3];
                st_bypass_f4(hs + (R0 + rl) * 128 + hc * 16 + q * 4, v);
            }
        }
        grid_barrier_nf(flags, gen, seq++);   // fence-free: weights stay cached
    }
}

extern "C" void kernel_launch(void* const* d_in, const int* in_sizes, int n_in,
                              void* d_out, int out_size, void* d_ws, size_t ws_size,
                              hipStream_t stream) {
    const float* observed = (const float*)d_in[0];
    const float* W_pos    = (const float*)d_in[1];
    const float* b_pos    = (const float*)d_in[2];
    const float* W_pool   = (const float*)d_in[3];
    const float* b_pool   = (const float*)d_in[4];
    const float* Wih_e    = (const float*)d_in[5];
    const float* bih_e    = (const float*)d_in[6];
    const float* Whh_e    = (const float*)d_in[7];
    const float* bhh_e    = (const float*)d_in[8];
    const float* Wih_d    = (const float*)d_in[9];
    const float* bih_d    = (const float*)d_in[10];
    const float* Whh_d    = (const float*)d_in[11];
    const float* bhh_d    = (const float*)d_in[12];
    const float* W_out    = (const float*)d_in[13];
    const float* b_out    = (const float*)d_in[14];
    float* outp = (float*)d_out;
    float* wsp  = (float*)d_ws;
    int npred = out_size / 1024;

    hipMemsetAsync(d_ws, 0, 33024, stream);   // flags + gen + cnt_rt

    social_lstm<<<NBLK, NTHR, LDS_BYTES, stream>>>(
        observed, W_pos, b_pos, W_pool, b_pool,
        Wih_e, bih_e, Whh_e, bhh_e,
        Wih_d, bih_d, Whh_d, bhh_d,
        W_out, b_out, outp, wsp, npred);
}

// Round 12
// 651.830 us; speedup vs baseline: 2.0539x; 1.0595x over previous
//
#include <hip/hip_runtime.h>
#include <math.h>

#define NBLK 256
#define NTHR 512

// ---- ws layout ----
// uints: [b*16] arrival flags (b<256); [4096] gen; [4112 + (rt*8+kc)*16] rt-flags
// floats from 8256:
#define OFF_OBS     8256        // 8192   (cached, immutable after init barrier)
#define OFF_HS      16448       // 65536  (BYPASS/LLC domain after init)
#define OFF_PART    81984       // 524288 (BYPASS domain)
#define OFF_WTPOOL  606272      // 262144 (Wt_pool [2048][128], cached immutable)
#define OFF_WTG_E   868416      // 163840 (cached immutable)
#define OFF_WTG_D   1032256     // 163840 (cached immutable)

#define LDS_BYTES 30848

typedef float vf4 __attribute__((ext_vector_type(4)));
typedef float vf2 __attribute__((ext_vector_type(2)));

// ---------- L2-bypass (LLC-coherent) access ----------
__device__ __forceinline__ void st_bypass_f4(float* p, vf4 v) {
    asm volatile("global_store_dwordx4 %0, %1, off sc0 sc1" :: "v"(p), "v"(v) : "memory");
}
__device__ __forceinline__ void st_bypass_f2(float* p, vf2 v) {
    asm volatile("global_store_dwordx2 %0, %1, off sc0 sc1" :: "v"(p), "v"(v) : "memory");
}
__device__ __forceinline__ vf4 ld_bypass_f4(const float* p) {
    vf4 v;
    asm volatile("global_load_dwordx4 %0, %1, off sc0 sc1\n\ts_waitcnt vmcnt(0)"
                 : "=&v"(v) : "v"(p) : "memory");
    return v;
}
__device__ __forceinline__ void ld_bypass_f4x8(const float* b, int stride, vf4* v) {
    asm volatile(
        "global_load_dwordx4 %0, %8, off sc0 sc1\n\t"
        "global_load_dwordx4 %1, %9, off sc0 sc1\n\t"
        "global_load_dwordx4 %2, %10, off sc0 sc1\n\t"
        "global_load_dwordx4 %3, %11, off sc0 sc1\n\t"
        "global_load_dwordx4 %4, %12, off sc0 sc1\n\t"
        "global_load_dwordx4 %5, %13, off sc0 sc1\n\t"
        "global_load_dwordx4 %6, %14, off sc0 sc1\n\t"
        "global_load_dwordx4 %7, %15, off sc0 sc1\n\t"
        "s_waitcnt vmcnt(0)"
        : "=&v"(v[0]), "=&v"(v[1]), "=&v"(v[2]), "=&v"(v[3]),
          "=&v"(v[4]), "=&v"(v[5]), "=&v"(v[6]), "=&v"(v[7])
        : "v"(b), "v"(b + stride), "v"(b + 2 * stride), "v"(b + 3 * stride),
          "v"(b + 4 * stride), "v"(b + 5 * stride), "v"(b + 6 * stride), "v"(b + 7 * stride)
        : "memory");
}
// Batched gather: 8 entries x 32B (2 dwordx4 each), ONE waitcnt for all 16 loads.
// (Round 11 used per-entry relaxed-atomic loads -> compiler couldn't pipeline,
//  each entry paid a full LLC round trip; dense 96-entry cells cost ~14us.)
__device__ __forceinline__ void ld_gather8(
    const float* a0, const float* a1, const float* a2, const float* a3,
    const float* a4, const float* a5, const float* a6, const float* a7, vf4* v) {
    asm volatile(
        "global_load_dwordx4 %0, %16, off sc0 sc1\n\t"
        "global_load_dwordx4 %1, %16, off offset:16 sc0 sc1\n\t"
        "global_load_dwordx4 %2, %17, off sc0 sc1\n\t"
        "global_load_dwordx4 %3, %17, off offset:16 sc0 sc1\n\t"
        "global_load_dwordx4 %4, %18, off sc0 sc1\n\t"
        "global_load_dwordx4 %5, %18, off offset:16 sc0 sc1\n\t"
        "global_load_dwordx4 %6, %19, off sc0 sc1\n\t"
        "global_load_dwordx4 %7, %19, off offset:16 sc0 sc1\n\t"
        "global_load_dwordx4 %8, %20, off sc0 sc1\n\t"
        "global_load_dwordx4 %9, %20, off offset:16 sc0 sc1\n\t"
        "global_load_dwordx4 %10, %21, off sc0 sc1\n\t"
        "global_load_dwordx4 %11, %21, off offset:16 sc0 sc1\n\t"
        "global_load_dwordx4 %12, %22, off sc0 sc1\n\t"
        "global_load_dwordx4 %13, %22, off offset:16 sc0 sc1\n\t"
        "global_load_dwordx4 %14, %23, off sc0 sc1\n\t"
        "global_load_dwordx4 %15, %23, off offset:16 sc0 sc1\n\t"
        "s_waitcnt vmcnt(0)"
        : "=&v"(v[0]), "=&v"(v[1]), "=&v"(v[2]), "=&v"(v[3]),
          "=&v"(v[4]), "=&v"(v[5]), "=&v"(v[6]), "=&v"(v[7]),
          "=&v"(v[8]), "=&v"(v[9]), "=&v"(v[10]), "=&v"(v[11]),
          "=&v"(v[12]), "=&v"(v[13]), "=&v"(v[14]), "=&v"(v[15])
        : "v"(a0), "v"(a1), "v"(a2), "v"(a3), "v"(a4), "v"(a5), "v"(a6), "v"(a7)
        : "memory");
}
__device__ __forceinline__ float ld_cohere(const float* p) {
    return __hip_atomic_load(p, __ATOMIC_RELAXED, __HIP_MEMORY_SCOPE_AGENT);
}

// Fenced barrier (init only).
__device__ __forceinline__ void grid_barrier_fenced(unsigned* flags, unsigned* gen, unsigned seq) {
    __syncthreads();
    if (threadIdx.x == 0)
        __builtin_amdgcn_fence(__ATOMIC_RELEASE, "agent");
    if (blockIdx.x == 0) {
        if (threadIdx.x < 64) {
            #pragma unroll
            for (int q = 0; q < 4; q++) {
                int bb = threadIdx.x * 4 + q;
                if (bb != 0) {
                    while (__hip_atomic_load(&flags[bb * 16], __ATOMIC_RELAXED,
                                             __HIP_MEMORY_SCOPE_AGENT) != seq)
                        __builtin_amdgcn_s_sleep(1);
                }
            }
        }
        __syncthreads();
        if (threadIdx.x == 0) {
            __hip_atomic_store(gen, seq, __ATOMIC_RELAXED, __HIP_MEMORY_SCOPE_AGENT);
            __builtin_amdgcn_fence(__ATOMIC_ACQUIRE, "agent");
        }
    } else {
        if (threadIdx.x == 0) {
            __hip_atomic_store(&flags[blockIdx.x * 16], seq, __ATOMIC_RELAXED,
                               __HIP_MEMORY_SCOPE_AGENT);
            while (__hip_atomic_load(gen, __ATOMIC_RELAXED,
                                     __HIP_MEMORY_SCOPE_AGENT) != seq)
                __builtin_amdgcn_s_sleep(2);
            __builtin_amdgcn_fence(__ATOMIC_ACQUIRE, "agent");
        }
    }
    __syncthreads();
}

// Fence-free steady-state barrier (all cross-block mutable data at LLC).
__device__ __forceinline__ void grid_barrier_nf(unsigned* flags, unsigned* gen, unsigned seq) {
    __syncthreads();
    if (blockIdx.x == 0) {
        if (threadIdx.x < 64) {
            #pragma unroll
            for (int q = 0; q < 4; q++) {
                int bb = threadIdx.x * 4 + q;
                if (bb != 0) {
                    while (__hip_atomic_load(&flags[bb * 16], __ATOMIC_RELAXED,
                                             __HIP_MEMORY_SCOPE_AGENT) != seq)
                        __builtin_amdgcn_s_sleep(1);
                }
            }
        }
        __syncthreads();
        if (threadIdx.x == 0)
            __hip_atomic_store(gen, seq, __ATOMIC_RELAXED, __HIP_MEMORY_SCOPE_AGENT);
    } else {
        if (threadIdx.x == 0) {
            __hip_atomic_store(&flags[blockIdx.x * 16], seq, __ATOMIC_RELAXED,
                               __HIP_MEMORY_SCOPE_AGENT);
            while (__hip_atomic_load(gen, __ATOMIC_RELAXED,
                                     __HIP_MEMORY_SCOPE_AGENT) != seq)
                __builtin_amdgcn_s_sleep(2);
        }
    }
    __syncthreads();
}

__device__ __forceinline__ float sigm(float x) { return 1.f / (1.f + expf(-x)); }

__global__ void __launch_bounds__(NTHR, 1) social_lstm(
    const float* __restrict__ observed,
    const float* __restrict__ W_pos, const float* __restrict__ b_pos,
    const float* __restrict__ W_pool, const float* __restrict__ b_pool,
    const float* __restrict__ Wih_e, const float* __restrict__ bih_e,
    const float* __restrict__ Whh_e, const float* __restrict__ bhh_e,
    const float* __restrict__ Wih_d, const float* __restrict__ bih_d,
    const float* __restrict__ Whh_d, const float* __restrict__ bhh_d,
    const float* __restrict__ W_out, const float* __restrict__ b_out,
    float* __restrict__ out, float* __restrict__ ws, int npred)
{
    extern __shared__ char smem_raw[];
    const int t = threadIdx.x, b = blockIdx.x;
    const int gid = b * NTHR + t;

    unsigned* flags  = (unsigned*)ws;
    unsigned* gen    = flags + 4096;
    unsigned* rtf    = flags + 4112;            // (rt*8+kc)*16
    float* obs     = ws + OFF_OBS;
    float* hs      = ws + OFF_HS;
    float* part    = ws + OFF_PART;
    float* Wt_pool = ws + OFF_WTPOOL;
    float* Wt_ge   = ws + OFF_WTG_E;
    float* Wt_gd   = ws + OFF_WTG_D;
    unsigned seq = 1;

    // ================= init =================
    if (gid < 65536) hs[gid] = 0.f;
    if (gid < 512) {
        float vx[8], vy[8];
        int fin = 0;
        for (int tt = 0; tt < 8; tt++) {
            float x = observed[tt * 1024 + gid * 2];
            float y = observed[tt * 1024 + gid * 2 + 1];
            vx[tt] = x; vy[tt] = y;
            if (isfinite(x) && isfinite(y)) fin |= (1 << tt);
        }
        int firstv = -1;
        for (int tt = 7; tt >= 0; tt--) if (fin & (1 << tt)) firstv = tt;
        int last = -1;
        for (int tt = 0; tt < 8; tt++) {
            if (fin & (1 << tt)) last = tt;
            int take = (last >= 0) ? last : firstv;
            float ox = 0.f, oy = 0.f;
            if (take >= 0) { ox = vx[take]; oy = vy[take]; }
            obs[tt * 1024 + gid * 2]     = ox;
            obs[tt * 1024 + gid * 2 + 1] = oy;
        }
    }
    if (gid < 65536) {   // Wt_pool[k][p] = W_pool[p][k]
        int p = gid >> 9, k4 = gid & 511;
        float4 v = *(const float4*)(W_pool + p * 2048 + k4 * 4);
        float* dst = Wt_pool + (k4 * 4) * 128 + p;
        dst[0] = v.x; dst[128] = v.y; dst[256] = v.z; dst[384] = v.w;
    }
    for (int idx = gid; idx < 163840; idx += NBLK * NTHR) {
        int k = idx >> 9, o = idx & 511;
        float ve, vd;
        if (k < 192) { ve = Wih_e[o * 192 + k];       vd = Wih_d[o * 192 + k]; }
        else         { ve = Whh_e[o * 128 + k - 192]; vd = Whh_d[o * 128 + k - 192]; }
        Wt_ge[idx] = ve; Wt_gd[idx] = vd;
    }
    grid_barrier_fenced(flags, gen, seq++);

    const int rt = b >> 3, kc = b & 7, hc = kc;
    const int R0 = rt * 16;
    float cs_reg = 0.f;       // t<256: rl=t>>4, hh=t&15
    const int nstep = 7 + npred;

    for (int s = 0; s < nstep; s++) {
        const float* posp  = (s < 7) ? (obs + (s + 1) * 1024)
                                     : ((s == 7) ? (obs + 7 * 1024) : (out + (s - 8) * 1024));
        const float* prevp = (s < 7) ? (obs + s * 1024)
                                     : ((s <= 8) ? (obs + 7 * 1024) : (out + (s - 9) * 1024));
        const float* Wt_g = (s < 7) ? Wt_ge : Wt_gd;
        const float* bihp = (s < 7) ? bih_e : bih_d;
        const float* bhhp = (s < 7) ? bhh_e : bhh_d;

        // ===== Phase AB: pooling (2 cells) + soc GEMM K-chunk =====
        {
            float* pos2 = (float*)smem_raw;                           // 1024 f
            int* cnt    = (int*)(smem_raw + 4096);                    // 32 i
            unsigned short* lst = (unsigned short*)(smem_raw + 4224); // 32*96 us
            float* AsT  = (float*)(smem_raw + 10368);                 // 256*20 f

            if (t < 256) {
                if (s < 8) ((float4*)pos2)[t] = ((const float4*)posp)[t];   // obs: cached
                else       ((vf4*)pos2)[t] = ld_bypass_f4(posp + t * 4);    // out: LLC
            }
            if (t < 32) cnt[t] = 0;
            __syncthreads();

            if (kc == 1 && s >= 7 && t < 16) {  // init out row = pos + b_out (bypass)
                int i = R0 + t;
                vf2 v;
                v.x = pos2[2 * i] + b_out[0];
                v.y = pos2[2 * i + 1] + b_out[1];
                st_bypass_f2(out + (s - 7) * 1024 + 2 * i, v);
            }
            {   // pair eval: agent a = t>>5, 32 threads/agent
                int a = t >> 5, i = R0 + a;
                float pix = pos2[2 * i], piy = pos2[2 * i + 1];
                int c0 = kc * 2;
                for (int jj = 0; jj < 16; jj++) {
                    int j = (t & 31) + jj * 32;
                    float dx = pos2[2 * j]     - pix;
                    float dy = pos2[2 * j + 1] - piy;
                    if (j != i && fabsf(dx) <= 1.0f && fabsf(dy) <= 1.0f) {
                        int gx = (int)floorf((dx + 1.0f) * 2.0f); gx = gx < 0 ? 0 : (gx > 3 ? 3 : gx);
                        int gy = (int)floorf((dy + 1.0f) * 2.0f); gy = gy < 0 ? 0 : (gy > 3 ? 3 : gy);
                        int cc = gx * 4 + gy - c0;
                        if (cc == 0 || cc == 1) {
                            int slot = atomicAdd(&cnt[a * 2 + cc], 1);
                            if (slot < 96) lst[(a * 2 + cc) * 96 + slot] = (unsigned short)j;
                        }
                    }
                }
            }
            __syncthreads();
            {   // cell max -> AsT[k][agent]: thread = (a, cc, hq); batched pipelined gather
                int a = t >> 5, cc = (t >> 4) & 1, hq = t & 15;
                int len = cnt[a * 2 + cc]; if (len > 96) len = 96;
                float m[8];
                #pragma unroll
                for (int u = 0; u < 8; u++) m[u] = -3.0e38f;
                const unsigned short* ll = lst + (a * 2 + cc) * 96;
                for (int e = 0; e < len; e += 8) {
                    const float* ap[8];
                    #pragma unroll
                    for (int k2 = 0; k2 < 8; k2++) {
                        int ee = e + k2; if (ee >= len) ee = len - 1;   // pad: max is idempotent
                        ap[k2] = hs + (int)ll[ee] * 128 + hq * 8;
                    }
                    vf4 v[16];
                    ld_gather8(ap[0], ap[1], ap[2], ap[3], ap[4], ap[5], ap[6], ap[7], v);
                    #pragma unroll
                    for (int k2 = 0; k2 < 8; k2++) {
                        vf4 lo = v[2 * k2], hi = v[2 * k2 + 1];
                        m[0] = fmaxf(m[0], lo.x); m[1] = fmaxf(m[1], lo.y);
                        m[2] = fmaxf(m[2], lo.z); m[3] = fmaxf(m[3], lo.w);
                        m[4] = fmaxf(m[4], hi.x); m[5] = fmaxf(m[5], hi.y);
                        m[6] = fmaxf(m[6], hi.z); m[7] = fmaxf(m[7], hi.w);
                    }
                }
                #pragma unroll
                for (int u = 0; u < 8; u++)
                    AsT[(cc * 128 + hq * 8 + u) * 20 + a] = (len > 0) ? m[u] : 0.f;
            }
            __syncthreads();
            {   // soc GEMM: 16r x 128o x K256; tile 4x8; in-wave 8-way ksplit
                int og = (t & 7) | (((t >> 6) & 1) << 3);
                int ks = (t >> 3) & 7;
                int rowg = t >> 7;
                float acc[4][8];
                #pragma unroll
                for (int r = 0; r < 4; r++)
                    #pragma unroll
                    for (int o = 0; o < 8; o++) acc[r][o] = 0.f;
                const float4* W4 = (const float4*)Wt_pool;   // L2-resident all 19 steps
                int kb = kc * 256 + ks * 32;
                #pragma unroll 4
                for (int kk = 0; kk < 32; kk++) {
                    int kl = ks * 32 + kk;
                    float4 a4 = *(const float4*)&AsT[kl * 20 + rowg * 4];
                    float4 w0 = W4[(kb + kk) * 32 + og * 2];
                    float4 w1 = W4[(kb + kk) * 32 + og * 2 + 1];
                    float ar[4] = {a4.x, a4.y, a4.z, a4.w};
                    float wo[8] = {w0.x, w0.y, w0.z, w0.w, w1.x, w1.y, w1.z, w1.w};
                    #pragma unroll
                    for (int r = 0; r < 4; r++)
                        #pragma unroll
                        for (int o = 0; o < 8; o++)
                            acc[r][o] = fmaf(ar[r], wo[o], acc[r][o]);
                }
                #pragma unroll
                for (int r = 0; r < 4; r++)
                    #pragma unroll
                    for (int o = 0; o < 8; o++) {
                        acc[r][o] += __shfl_xor(acc[r][o], 8);
                        acc[r][o] += __shfl_xor(acc[r][o], 16);
                        acc[r][o] += __shfl_xor(acc[r][o], 32);
                    }
                if ((t & 56) == 0) {
                    #pragma unroll
                    for (int r = 0; r < 4; r++) {
                        int row = R0 + rowg * 4 + r;
                        float* pp = part + kc * 65536 + row * 128 + og * 8;
                        vf4 lo, hi;
                        lo.x = acc[r][0]; lo.y = acc[r][1]; lo.z = acc[r][2]; lo.w = acc[r][3];
                        hi.x = acc[r][4]; hi.y = acc[r][5]; hi.z = acc[r][6]; hi.w = acc[r][7];
                        st_bypass_f4(pp,     lo);
                        st_bypass_f4(pp + 4, hi);
                    }
                }
            }
        }

        // ===== rt-sync (parallel flags) overlapped with CD staging =====
        __syncthreads();                 // drains this block's bypass stores (vmcnt)
        if (t == 0)
            __hip_atomic_store(&rtf[(rt * 8 + kc) * 16], (unsigned)(s + 1),
                               __ATOMIC_RELAXED, __HIP_MEMORY_SCOPE_AGENT);
        {
            float* AsT  = (float*)smem_raw;                 // [320][20]
            {   // stage emb rows (k 0..63): independent of part -> do before poll
                int r = t >> 5, e2 = (t & 31) * 2;
                int i2 = 2 * (R0 + r);
                float vx = ld_cohere(posp + i2)     - ld_cohere(prevp + i2);
                float vy = ld_cohere(posp + i2 + 1) - ld_cohere(prevp + i2 + 1);
                float e0 = fmaxf(W_pos[e2 * 2]     * vx + W_pos[e2 * 2 + 1] * vy + b_pos[e2],     0.f);
                float e1 = fmaxf(W_pos[e2 * 2 + 2] * vx + W_pos[e2 * 2 + 3] * vy + b_pos[e2 + 1], 0.f);
                AsT[(e2 + 0) * 20 + r] = e0;
                AsT[(e2 + 1) * 20 + r] = e1;
            }
            {   // stage hs rows (k 192..319): independent of part
                int r = t >> 5, h4 = (t & 31) * 4;
                vf4 v = ld_bypass_f4(hs + (R0 + r) * 128 + h4);
                AsT[(192 + h4 + 0) * 20 + r] = v.x;
                AsT[(192 + h4 + 1) * 20 + r] = v.y;
                AsT[(192 + h4 + 2) * 20 + r] = v.z;
                AsT[(192 + h4 + 3) * 20 + r] = v.w;
            }
            // poll the 8 producer flags in parallel
            if (t < 8) {
                while (__hip_atomic_load(&rtf[(rt * 8 + t) * 16], __ATOMIC_RELAXED,
                                         __HIP_MEMORY_SCOPE_AGENT) != (unsigned)(s + 1))
                    __builtin_amdgcn_s_sleep(1);
            }
            __syncthreads();
            {   // stage soc rows (k 64..191): bypass part reduce + bias + relu
                int r = t >> 5, p4 = (t & 31) * 4;
                vf4 pv[8];
                ld_bypass_f4x8(part + (R0 + r) * 128 + p4, 65536, pv);
                float sv[4] = {0.f, 0.f, 0.f, 0.f};
                #pragma unroll
                for (int kc2 = 0; kc2 < 8; kc2++) {
                    sv[0] += pv[kc2].x; sv[1] += pv[kc2].y;
                    sv[2] += pv[kc2].z; sv[3] += pv[kc2].w;
                }
                #pragma unroll
                for (int u = 0; u < 4; u++)
                    AsT[(64 + p4 + u) * 20 + r] = fmaxf(sv[u] + b_pool[p4 + u], 0.f);
            }
            __syncthreads();
            float* red  = (float*)(smem_raw + 25600);       // [16][64]
            float* hrow = (float*)(smem_raw + 29696);       // [16][16]
            {   // gates GEMM: 16r x 64o x K320; tile 4x4; in-wave 8-way ksplit
                int og = (t & 7) | (((t >> 6) & 1) << 3);
                int ks = (t >> 3) & 7;
                int rowg = t >> 7;
                int col4 = (og >> 2) * 32 + hc * 4 + (og & 3);
                float acc[4][4];
                #pragma unroll
                for (int r = 0; r < 4; r++)
                    #pragma unroll
                    for (int o = 0; o < 4; o++) acc[r][o] = 0.f;
                const float4* Wg4 = (const float4*)Wt_g;    // L2-resident
                #pragma unroll 4
                for (int kk = 0; kk < 40; kk++) {
                    int k = ks * 40 + kk;
                    float4 a4 = *(const float4*)&AsT[k * 20 + rowg * 4];
                    float4 w  = Wg4[k * 128 + col4];
                    float ar[4] = {a4.x, a4.y, a4.z, a4.w};
                    float wo[4] = {w.x, w.y, w.z, w.w};
                    #pragma unroll
                    for (int r = 0; r < 4; r++)
                        #pragma unroll
                        for (int o = 0; o < 4; o++)
                            acc[r][o] = fmaf(ar[r], wo[o], acc[r][o]);
                }
                #pragma unroll
                for (int r = 0; r < 4; r++)
                    #pragma unroll
                    for (int o = 0; o < 4; o++) {
                        acc[r][o] += __shfl_xor(acc[r][o], 8);
                        acc[r][o] += __shfl_xor(acc[r][o], 16);
                        acc[r][o] += __shfl_xor(acc[r][o], 32);
                    }
                if ((t & 56) == 0) {
                    #pragma unroll
                    for (int r = 0; r < 4; r++)
                        *(float4*)&red[(rowg * 4 + r) * 64 + og * 4] =
                            make_float4(acc[r][0], acc[r][1], acc[r][2], acc[r][3]);
                }
            }
            __syncthreads();
            if (t < 256) {   // pointwise LSTM
                int rl = t >> 4, hh = t & 15;
                float g4[4];
                #pragma unroll
                for (int q = 0; q < 4; q++) {
                    int colq = q * 128 + hc * 16 + hh;
                    g4[q] = red[rl * 64 + q * 16 + hh] + bihp[colq] + bhhp[colq];
                }
                float si = sigm(g4[0]);
                float sf = sigm(g4[1]);
                float so = sigm(g4[3]);
                float c2 = sf * cs_reg + si * tanhf(g4[2]);
                float h2 = so * tanhf(c2);
                cs_reg = c2;
                hrow[rl * 16 + hh] = h2;
                if (s >= 7) {
                    int i = R0 + rl, h = hc * 16 + hh;
                    float v0 = W_out[h] * h2;
                    float v1 = W_out[128 + h] * h2;
                    v0 += __shfl_down(v0, 8); v0 += __shfl_down(v0, 4);
                    v0 += __shfl_down(v0, 2); v0 += __shfl_down(v0, 1);
                    v1 += __shfl_down(v1, 8); v1 += __shfl_down(v1, 4);
                    v1 += __shfl_down(v1, 2); v1 += __shfl_down(v1, 1);
                    if (hh == 0) {
                        atomicAdd(&out[(s - 7) * 1024 + 2 * i],     v0);
                        atomicAdd(&out[(s - 7) * 1024 + 2 * i + 1], v1);
                    }
                }
            }
            __syncthreads();
            if (t < 64) {   // coalesced bypass hs writeback: 64B per agent h-slice
                int rl = t >> 2, q = t & 3;
                vf4 v;
                v.x = hrow[rl * 16 + q * 4 + 0];
                v.y = hrow[rl * 16 + q * 4 + 1];
                v.z = hrow[rl * 16 + q * 4 + 2];
                v.w = hrow[rl * 16 + q * 4 + 3];
                st_bypass_f4(hs + (R0 + rl) * 128 + hc * 16 + q * 4, v);
            }
        }
        grid_barrier_nf(flags, gen, seq++);   // fence-free: weights stay cached
    }
}

extern "C" void kernel_launch(void* const* d_in, const int* in_sizes, int n_in,
                              void* d_out, int out_size, void* d_ws, size_t ws_size,
                              hipStream_t stream) {
    const float* observed = (const float*)d_in[0];
    const float* W_pos    = (const float*)d_in[1];
    const float* b_pos    = (const float*)d_in[2];
    const float* W_pool   = (const float*)d_in[3];
    const float* b_pool   = (const float*)d_in[4];
    const float* Wih_e    = (const float*)d_in[5];
    const float* bih_e    = (const float*)d_in[6];
    const float* Whh_e    = (const float*)d_in[7];
    const float* bhh_e    = (const float*)d_in[8];
    const float* Wih_d    = (const float*)d_in[9];
    const float* bih_d    = (const float*)d_in[10];
    const float* Whh_d    = (const float*)d_in[11];
    const float* bhh_d    = (const float*)d_in[12];
    const float* W_out    = (const float*)d_in[13];
    const float* b_out    = (const float*)d_in[14];
    float* outp = (float*)d_out;
    float* wsp  = (float*)d_ws;
    int npred = out_size / 1024;

    hipMemsetAsync(d_ws, 0, 33024, stream);   // arrival flags + gen + rt flags

    social_lstm<<<NBLK, NTHR, LDS_BYTES, stream>>>(
        observed, W_pos, b_pos, W_pool, b_pool,
        Wih_e, bih_e, Whh_e, bhh_e,
        Wih_d, bih_d, Whh_d, bhh_d,
        W_out, b_out, outp, wsp, npred);
}

// Round 13
// 640.553 us; speedup vs baseline: 2.0901x; 1.0176x over previous
//
#include <hip/hip_runtime.h>
#include <math.h>

#define NBLK 256
#define NTHR 512

// ---- ws layout ----
// uints: [b*16] arrival flags (b<256); [4096] gen; [4112 + (rt*8+kc)*16] rt-flags
// floats from 8256:
#define OFF_OBS     8256        // 8192   (cached, immutable after init barrier)
#define OFF_HS      16448       // 65536  (BYPASS/LLC domain after init)
#define OFF_PART    81984       // 524288 (BYPASS domain)
#define OFF_WTPOOL  606272      // 262144 (Wt_pool [2048][128], cached immutable)
#define OFF_WTG_E   868416      // 163840 (cached immutable)
#define OFF_WTG_D   1032256     // 163840 (cached immutable)

#define LDS_BYTES 31232

typedef float vf4 __attribute__((ext_vector_type(4)));
typedef float vf2 __attribute__((ext_vector_type(2)));

// Swizzled AsT row offset: row*20 + 4-float pad every 32 rows.
// Plain stride-20 made 32-row-apart K-split groups differ by 640 floats = 0 mod 32
// -> 8-way LDS bank conflicts in both GEMM inner loops and 16-way on gather
// writes (SQ_LDS_BANK_CONFLICT 5.4e7 in r12 = ~4.6us/CU/step). With the pad,
// groups differ by 644 = 4 mod 32 -> the 8 b128 reads tile all 32 banks.
__device__ __forceinline__ int asr20(int row) { return row * 20 + ((row >> 5) << 2); }

// ---------- L2-bypass (LLC-coherent) access ----------
__device__ __forceinline__ void st_bypass_f4(float* p, vf4 v) {
    asm volatile("global_store_dwordx4 %0, %1, off sc0 sc1" :: "v"(p), "v"(v) : "memory");
}
__device__ __forceinline__ void st_bypass_f2(float* p, vf2 v) {
    asm volatile("global_store_dwordx2 %0, %1, off sc0 sc1" :: "v"(p), "v"(v) : "memory");
}
__device__ __forceinline__ vf4 ld_bypass_f4(const float* p) {
    vf4 v;
    asm volatile("global_load_dwordx4 %0, %1, off sc0 sc1\n\ts_waitcnt vmcnt(0)"
                 : "=&v"(v) : "v"(p) : "memory");
    return v;
}
__device__ __forceinline__ void ld_bypass_f4x8(const float* b, int stride, vf4* v) {
    asm volatile(
        "global_load_dwordx4 %0, %8, off sc0 sc1\n\t"
        "global_load_dwordx4 %1, %9, off sc0 sc1\n\t"
        "global_load_dwordx4 %2, %10, off sc0 sc1\n\t"
        "global_load_dwordx4 %3, %11, off sc0 sc1\n\t"
        "global_load_dwordx4 %4, %12, off sc0 sc1\n\t"
        "global_load_dwordx4 %5, %13, off sc0 sc1\n\t"
        "global_load_dwordx4 %6, %14, off sc0 sc1\n\t"
        "global_load_dwordx4 %7, %15, off sc0 sc1\n\t"
        "s_waitcnt vmcnt(0)"
        : "=&v"(v[0]), "=&v"(v[1]), "=&v"(v[2]), "=&v"(v[3]),
          "=&v"(v[4]), "=&v"(v[5]), "=&v"(v[6]), "=&v"(v[7])
        : "v"(b), "v"(b + stride), "v"(b + 2 * stride), "v"(b + 3 * stride),
          "v"(b + 4 * stride), "v"(b + 5 * stride), "v"(b + 6 * stride), "v"(b + 7 * stride)
        : "memory");
}
// Batched gather: 8 entries x 32B (2 dwordx4 each), ONE waitcnt for all 16 loads.
__device__ __forceinline__ void ld_gather8(
    const float* a0, const float* a1, const float* a2, const float* a3,
    const float* a4, const float* a5, const float* a6, const float* a7, vf4* v) {
    asm volatile(
        "global_load_dwordx4 %0, %16, off sc0 sc1\n\t"
        "global_load_dwordx4 %1, %16, off offset:16 sc0 sc1\n\t"
        "global_load_dwordx4 %2, %17, off sc0 sc1\n\t"
        "global_load_dwordx4 %3, %17, off offset:16 sc0 sc1\n\t"
        "global_load_dwordx4 %4, %18, off sc0 sc1\n\t"
        "global_load_dwordx4 %5, %18, off offset:16 sc0 sc1\n\t"
        "global_load_dwordx4 %6, %19, off sc0 sc1\n\t"
        "global_load_dwordx4 %7, %19, off offset:16 sc0 sc1\n\t"
        "global_load_dwordx4 %8, %20, off sc0 sc1\n\t"
        "global_load_dwordx4 %9, %20, off offset:16 sc0 sc1\n\t"
        "global_load_dwordx4 %10, %21, off sc0 sc1\n\t"
        "global_load_dwordx4 %11, %21, off offset:16 sc0 sc1\n\t"
        "global_load_dwordx4 %12, %22, off sc0 sc1\n\t"
        "global_load_dwordx4 %13, %22, off offset:16 sc0 sc1\n\t"
        "global_load_dwordx4 %14, %23, off sc0 sc1\n\t"
        "global_load_dwordx4 %15, %23, off offset:16 sc0 sc1\n\t"
        "s_waitcnt vmcnt(0)"
        : "=&v"(v[0]), "=&v"(v[1]), "=&v"(v[2]), "=&v"(v[3]),
          "=&v"(v[4]), "=&v"(v[5]), "=&v"(v[6]), "=&v"(v[7]),
          "=&v"(v[8]), "=&v"(v[9]), "=&v"(v[10]), "=&v"(v[11]),
          "=&v"(v[12]), "=&v"(v[13]), "=&v"(v[14]), "=&v"(v[15])
        : "v"(a0), "v"(a1), "v"(a2), "v"(a3), "v"(a4), "v"(a5), "v"(a6), "v"(a7)
        : "memory");
}
__device__ __forceinline__ float ld_cohere(const float* p) {
    return __hip_atomic_load(p, __ATOMIC_RELAXED, __HIP_MEMORY_SCOPE_AGENT);
}

// Fenced barrier (init only).
__device__ __forceinline__ void grid_barrier_fenced(unsigned* flags, unsigned* gen, unsigned seq) {
    __syncthreads();
    if (threadIdx.x == 0)
        __builtin_amdgcn_fence(__ATOMIC_RELEASE, "agent");
    if (blockIdx.x == 0) {
        if (threadIdx.x < 64) {
            #pragma unroll
            for (int q = 0; q < 4; q++) {
                int bb = threadIdx.x * 4 + q;
                if (bb != 0) {
                    while (__hip_atomic_load(&flags[bb * 16], __ATOMIC_RELAXED,
                                             __HIP_MEMORY_SCOPE_AGENT) != seq)
                        __builtin_amdgcn_s_sleep(1);
                }
            }
        }
        __syncthreads();
        if (threadIdx.x == 0) {
            __hip_atomic_store(gen, seq, __ATOMIC_RELAXED, __HIP_MEMORY_SCOPE_AGENT);
            __builtin_amdgcn_fence(__ATOMIC_ACQUIRE, "agent");
        }
    } else {
        if (threadIdx.x == 0) {
            __hip_atomic_store(&flags[blockIdx.x * 16], seq, __ATOMIC_RELAXED,
                               __HIP_MEMORY_SCOPE_AGENT);
            while (__hip_atomic_load(gen, __ATOMIC_RELAXED,
                                     __HIP_MEMORY_SCOPE_AGENT) != seq)
                __builtin_amdgcn_s_sleep(2);
            __builtin_amdgcn_fence(__ATOMIC_ACQUIRE, "agent");
        }
    }
    __syncthreads();
}

// Fence-free steady-state barrier (all cross-block mutable data at LLC).
__device__ __forceinline__ void grid_barrier_nf(unsigned* flags, unsigned* gen, unsigned seq) {
    __syncthreads();
    if (blockIdx.x == 0) {
        if (threadIdx.x < 64) {
            #pragma unroll
            for (int q = 0; q < 4; q++) {
                int bb = threadIdx.x * 4 + q;
                if (bb != 0) {
                    while (__hip_atomic_load(&flags[bb * 16], __ATOMIC_RELAXED,
                                             __HIP_MEMORY_SCOPE_AGENT) != seq)
                        __builtin_amdgcn_s_sleep(1);
                }
            }
        }
        __syncthreads();
        if (threadIdx.x == 0)
            __hip_atomic_store(gen, seq, __ATOMIC_RELAXED, __HIP_MEMORY_SCOPE_AGENT);
    } else {
        if (threadIdx.x == 0) {
            __hip_atomic_store(&flags[blockIdx.x * 16], seq, __ATOMIC_RELAXED,
                               __HIP_MEMORY_SCOPE_AGENT);
            while (__hip_atomic_load(gen, __ATOMIC_RELAXED,
                                     __HIP_MEMORY_SCOPE_AGENT) != seq)
                __builtin_amdgcn_s_sleep(2);
        }
    }
    __syncthreads();
}

__device__ __forceinline__ float sigm(float x) { return 1.f / (1.f + expf(-x)); }

__global__ void __launch_bounds__(NTHR, 1) social_lstm(
    const float* __restrict__ observed,
    const float* __restrict__ W_pos, const float* __restrict__ b_pos,
    const float* __restrict__ W_pool, const float* __restrict__ b_pool,
    const float* __restrict__ Wih_e, const float* __restrict__ bih_e,
    const float* __restrict__ Whh_e, const float* __restrict__ bhh_e,
    const float* __restrict__ Wih_d, const float* __restrict__ bih_d,
    const float* __restrict__ Whh_d, const float* __restrict__ bhh_d,
    const float* __restrict__ W_out, const float* __restrict__ b_out,
    float* __restrict__ out, float* __restrict__ ws, int npred)
{
    extern __shared__ char smem_raw[];
    const int t = threadIdx.x, b = blockIdx.x;
    const int gid = b * NTHR + t;

    unsigned* flags  = (unsigned*)ws;
    unsigned* gen    = flags + 4096;
    unsigned* rtf    = flags + 4112;            // (rt*8+kc)*16
    float* obs     = ws + OFF_OBS;
    float* hs      = ws + OFF_HS;
    float* part    = ws + OFF_PART;
    float* Wt_pool = ws + OFF_WTPOOL;
    float* Wt_ge   = ws + OFF_WTG_E;
    float* Wt_gd   = ws + OFF_WTG_D;
    unsigned seq = 1;

    // ================= init =================
    if (gid < 65536) hs[gid] = 0.f;
    if (gid < 512) {
        float vx[8], vy[8];
        int fin = 0;
        for (int tt = 0; tt < 8; tt++) {
            float x = observed[tt * 1024 + gid * 2];
            float y = observed[tt * 1024 + gid * 2 + 1];
            vx[tt] = x; vy[tt] = y;
            if (isfinite(x) && isfinite(y)) fin |= (1 << tt);
        }
        int firstv = -1;
        for (int tt = 7; tt >= 0; tt--) if (fin & (1 << tt)) firstv = tt;
        int last = -1;
        for (int tt = 0; tt < 8; tt++) {
            if (fin & (1 << tt)) last = tt;
            int take = (last >= 0) ? last : firstv;
            float ox = 0.f, oy = 0.f;
            if (take >= 0) { ox = vx[take]; oy = vy[take]; }
            obs[tt * 1024 + gid * 2]     = ox;
            obs[tt * 1024 + gid * 2 + 1] = oy;
        }
    }
    if (gid < 65536) {   // Wt_pool[k][p] = W_pool[p][k]
        int p = gid >> 9, k4 = gid & 511;
        float4 v = *(const float4*)(W_pool + p * 2048 + k4 * 4);
        float* dst = Wt_pool + (k4 * 4) * 128 + p;
        dst[0] = v.x; dst[128] = v.y; dst[256] = v.z; dst[384] = v.w;
    }
    for (int idx = gid; idx < 163840; idx += NBLK * NTHR) {
        int k = idx >> 9, o = idx & 511;
        float ve, vd;
        if (k < 192) { ve = Wih_e[o * 192 + k];       vd = Wih_d[o * 192 + k]; }
        else         { ve = Whh_e[o * 128 + k - 192]; vd = Whh_d[o * 128 + k - 192]; }
        Wt_ge[idx] = ve; Wt_gd[idx] = vd;
    }
    grid_barrier_fenced(flags, gen, seq++);

    const int rt = b >> 3, kc = b & 7, hc = kc;
    const int R0 = rt * 16;
    float cs_reg = 0.f;       // t<256: rl=t>>4, hh=t&15
    const int nstep = 7 + npred;

    for (int s = 0; s < nstep; s++) {
        const float* posp  = (s < 7) ? (obs + (s + 1) * 1024)
                                     : ((s == 7) ? (obs + 7 * 1024) : (out + (s - 8) * 1024));
        const float* prevp = (s < 7) ? (obs + s * 1024)
                                     : ((s <= 8) ? (obs + 7 * 1024) : (out + (s - 9) * 1024));
        const float* Wt_g = (s < 7) ? Wt_ge : Wt_gd;
        const float* bihp = (s < 7) ? bih_e : bih_d;
        const float* bhhp = (s < 7) ? bhh_e : bhh_d;

        // ===== Phase AB: pooling (2 cells) + soc GEMM K-chunk =====
        {
            float* pos2 = (float*)smem_raw;                           // 1024 f
            int* cnt    = (int*)(smem_raw + 4096);                    // 32 i
            unsigned short* lst = (unsigned short*)(smem_raw + 4224); // 32*96 us
            float* AsT  = (float*)(smem_raw + 10368);                 // swizzled [256 rows][20]

            if (t < 256) {
                if (s < 8) ((float4*)pos2)[t] = ((const float4*)posp)[t];   // obs: cached
                else       ((vf4*)pos2)[t] = ld_bypass_f4(posp + t * 4);    // out: LLC
            }
            if (t < 32) cnt[t] = 0;
            __syncthreads();

            if (kc == 1 && s >= 7 && t < 16) {  // init out row = pos + b_out (bypass)
                int i = R0 + t;
                vf2 v;
                v.x = pos2[2 * i] + b_out[0];
                v.y = pos2[2 * i + 1] + b_out[1];
                st_bypass_f2(out + (s - 7) * 1024 + 2 * i, v);
            }
            {   // pair eval: agent a = t>>5, 32 threads/agent
                int a = t >> 5, i = R0 + a;
                float pix = pos2[2 * i], piy = pos2[2 * i + 1];
                int c0 = kc * 2;
                for (int jj = 0; jj < 16; jj++) {
                    int j = (t & 31) + jj * 32;
                    float dx = pos2[2 * j]     - pix;
                    float dy = pos2[2 * j + 1] - piy;
                    if (j != i && fabsf(dx) <= 1.0f && fabsf(dy) <= 1.0f) {
                        int gx = (int)floorf((dx + 1.0f) * 2.0f); gx = gx < 0 ? 0 : (gx > 3 ? 3 : gx);
                        int gy = (int)floorf((dy + 1.0f) * 2.0f); gy = gy < 0 ? 0 : (gy > 3 ? 3 : gy);
                        int cc = gx * 4 + gy - c0;
                        if (cc == 0 || cc == 1) {
                            int slot = atomicAdd(&cnt[a * 2 + cc], 1);
                            if (slot < 96) lst[(a * 2 + cc) * 96 + slot] = (unsigned short)j;
                        }
                    }
                }
            }
            __syncthreads();
            {   // cell max -> AsT[k][agent]: thread = (a, cc, hq); batched pipelined gather
                int a = t >> 5, cc = (t >> 4) & 1, hq = t & 15;
                int len = cnt[a * 2 + cc]; if (len > 96) len = 96;
                float m[8];
                #pragma unroll
                for (int u = 0; u < 8; u++) m[u] = -3.0e38f;
                const unsigned short* ll = lst + (a * 2 + cc) * 96;
                for (int e = 0; e < len; e += 8) {
                    const float* ap[8];
                    #pragma unroll
                    for (int k2 = 0; k2 < 8; k2++) {
                        int ee = e + k2; if (ee >= len) ee = len - 1;   // pad: max is idempotent
                        ap[k2] = hs + (int)ll[ee] * 128 + hq * 8;
                    }
                    vf4 v[16];
                    ld_gather8(ap[0], ap[1], ap[2], ap[3], ap[4], ap[5], ap[6], ap[7], v);
                    #pragma unroll
                    for (int k2 = 0; k2 < 8; k2++) {
                        vf4 lo = v[2 * k2], hi = v[2 * k2 + 1];
                        m[0] = fmaxf(m[0], lo.x); m[1] = fmaxf(m[1], lo.y);
                        m[2] = fmaxf(m[2], lo.z); m[3] = fmaxf(m[3], lo.w);
                        m[4] = fmaxf(m[4], hi.x); m[5] = fmaxf(m[5], hi.y);
                        m[6] = fmaxf(m[6], hi.z); m[7] = fmaxf(m[7], hi.w);
                    }
                }
                #pragma unroll
                for (int u = 0; u < 8; u++)
                    AsT[asr20(cc * 128 + hq * 8 + u) + a] = (len > 0) ? m[u] : 0.f;
            }
            __syncthreads();
            {   // soc GEMM: 16r x 128o x K256; tile 4x8; in-wave 8-way ksplit
                int og = (t & 7) | (((t >> 6) & 1) << 3);
                int ks = (t >> 3) & 7;
                int rowg = t >> 7;
                float acc[4][8];
                #pragma unroll
                for (int r = 0; r < 4; r++)
                    #pragma unroll
                    for (int o = 0; o < 8; o++) acc[r][o] = 0.f;
                const float4* W4 = (const float4*)Wt_pool;   // L2-resident all 19 steps
                int kb = kc * 256 + ks * 32;
                #pragma unroll 4
                for (int kk = 0; kk < 32; kk++) {
                    int kl = ks * 32 + kk;
                    float4 a4 = *(const float4*)&AsT[asr20(kl) + rowg * 4];
                    float4 w0 = W4[(kb + kk) * 32 + og * 2];
                    float4 w1 = W4[(kb + kk) * 32 + og * 2 + 1];
                    float ar[4] = {a4.x, a4.y, a4.z, a4.w};
                    float wo[8] = {w0.x, w0.y, w0.z, w0.w, w1.x, w1.y, w1.z, w1.w};
                    #pragma unroll
                    for (int r = 0; r < 4; r++)
                        #pragma unroll
                        for (int o = 0; o < 8; o++)
                            acc[r][o] = fmaf(ar[r], wo[o], acc[r][o]);
                }
                #pragma unroll
                for (int r = 0; r < 4; r++)
                    #pragma unroll
                    for (int o = 0; o < 8; o++) {
                        acc[r][o] += __shfl_xor(acc[r][o], 8);
                        acc[r][o] += __shfl_xor(acc[r][o], 16);
                        acc[r][o] += __shfl_xor(acc[r][o], 32);
                    }
                if ((t & 56) == 0) {
                    #pragma unroll
                    for (int r = 0; r < 4; r++) {
                        int row = R0 + rowg * 4 + r;
                        float* pp = part + kc * 65536 + row * 128 + og * 8;
                        vf4 lo, hi;
                        lo.x = acc[r][0]; lo.y = acc[r][1]; lo.z = acc[r][2]; lo.w = acc[r][3];
                        hi.x = acc[r][4]; hi.y = acc[r][5]; hi.z = acc[r][6]; hi.w = acc[r][7];
                        st_bypass_f4(pp,     lo);
                        st_bypass_f4(pp + 4, hi);
                    }
                }
            }
        }

        // ===== rt-sync (parallel flags) overlapped with CD staging =====
        __syncthreads();                 // drains this block's bypass stores (vmcnt)
        if (t == 0)
            __hip_atomic_store(&rtf[(rt * 8 + kc) * 16], (unsigned)(s + 1),
                               __ATOMIC_RELAXED, __HIP_MEMORY_SCOPE_AGENT);
        {
            float* AsT  = (float*)smem_raw;                 // swizzled [320 rows][20]
            {   // stage emb rows (k 0..63): independent of part -> do before poll
                int r = t >> 5, e2 = (t & 31) * 2;
                int i2 = 2 * (R0 + r);
                float vx = ld_cohere(posp + i2)     - ld_cohere(prevp + i2);
                float vy = ld_cohere(posp + i2 + 1) - ld_cohere(prevp + i2 + 1);
                float e0 = fmaxf(W_pos[e2 * 2]     * vx + W_pos[e2 * 2 + 1] * vy + b_pos[e2],     0.f);
                float e1 = fmaxf(W_pos[e2 * 2 + 2] * vx + W_pos[e2 * 2 + 3] * vy + b_pos[e2 + 1], 0.f);
                AsT[asr20(e2 + 0) + r] = e0;
                AsT[asr20(e2 + 1) + r] = e1;
            }
            {   // stage hs rows (k 192..319): independent of part
                int r = t >> 5, h4 = (t & 31) * 4;
                vf4 v = ld_bypass_f4(hs + (R0 + r) * 128 + h4);
                AsT[asr20(192 + h4 + 0) + r] = v.x;
                AsT[asr20(192 + h4 + 1) + r] = v.y;
                AsT[asr20(192 + h4 + 2) + r] = v.z;
                AsT[asr20(192 + h4 + 3) + r] = v.w;
            }
            // poll the 8 producer flags in parallel
            if (t < 8) {
                while (__hip_atomic_load(&rtf[(rt * 8 + t) * 16], __ATOMIC_RELAXED,
                                         __HIP_MEMORY_SCOPE_AGENT) != (unsigned)(s + 1))
                    __builtin_amdgcn_s_sleep(1);
            }
            __syncthreads();
            {   // stage soc rows (k 64..191): bypass part reduce + bias + relu
                int r = t >> 5, p4 = (t & 31) * 4;
                vf4 pv[8];
                ld_bypass_f4x8(part + (R0 + r) * 128 + p4, 65536, pv);
                float sv[4] = {0.f, 0.f, 0.f, 0.f};
                #pragma unroll
                for (int kc2 = 0; kc2 < 8; kc2++) {
                    sv[0] += pv[kc2].x; sv[1] += pv[kc2].y;
                    sv[2] += pv[kc2].z; sv[3] += pv[kc2].w;
                }
                #pragma unroll
                for (int u = 0; u < 4; u++)
                    AsT[asr20(64 + p4 + u) + r] = fmaxf(sv[u] + b_pool[p4 + u], 0.f);
            }
            __syncthreads();
            float* red  = (float*)(smem_raw + 25792);       // [16][64]
            float* hrow = (float*)(smem_raw + 29888);       // [16][16]
            {   // gates GEMM: 16r x 64o x K320; tile 4x4; in-wave 8-way ksplit
                int og = (t & 7) | (((t >> 6) & 1) << 3);
                int ks = (t >> 3) & 7;
                int rowg = t >> 7;
                int col4 = (og >> 2) * 32 + hc * 4 + (og & 3);
                float acc[4][4];
                #pragma unroll
                for (int r = 0; r < 4; r++)
                    #pragma unroll
                    for (int o = 0; o < 4; o++) acc[r][o] = 0.f;
                const float4* Wg4 = (const float4*)Wt_g;    // L2-resident
                #pragma unroll 4
                for (int kk = 0; kk < 40; kk++) {
                    int k = ks * 40 + kk;
                    float4 a4 = *(const float4*)&AsT[asr20(k) + rowg * 4];
                    float4 w  = Wg4[k * 128 + col4];
                    float ar[4] = {a4.x, a4.y, a4.z, a4.w};
                    float wo[4] = {w.x, w.y, w.z, w.w};
                    #pragma unroll
                    for (int r = 0; r < 4; r++)
                        #pragma unroll
                        for (int o = 0; o < 4; o++)
                            acc[r][o] = fmaf(ar[r], wo[o], acc[r][o]);
                }
                #pragma unroll
                for (int r = 0; r < 4; r++)
                    #pragma unroll
                    for (int o = 0; o < 4; o++) {
                        acc[r][o] += __shfl_xor(acc[r][o], 8);
                        acc[r][o] += __shfl_xor(acc[r][o], 16);
                        acc[r][o] += __shfl_xor(acc[r][o], 32);
                    }
                if ((t & 56) == 0) {
                    #pragma unroll
                    for (int r = 0; r < 4; r++)
                        *(float4*)&red[(rowg * 4 + r) * 64 + og * 4] =
                            make_float4(acc[r][0], acc[r][1], acc[r][2], acc[r][3]);
                }
            }
            __syncthreads();
            if (t < 256) {   // pointwise LSTM
                int rl = t >> 4, hh = t & 15;
                float g4[4];
                #pragma unroll
                for (int q = 0; q < 4; q++) {
                    int colq = q * 128 + hc * 16 + hh;
                    g4[q] = red[rl * 64 + q * 16 + hh] + bihp[colq] + bhhp[colq];
                }
                float si = sigm(g4[0]);
                float sf = sigm(g4[1]);
                float so = sigm(g4[3]);
                float c2 = sf * cs_reg + si * tanhf(g4[2]);
                float h2 = so * tanhf(c2);
                cs_reg = c2;
                hrow[rl * 16 + hh] = h2;
                if (s >= 7) {
                    int i = R0 + rl, h = hc * 16 + hh;
                    float v0 = W_out[h] * h2;
                    float v1 = W_out[128 + h] * h2;
                    v0 += __shfl_down(v0, 8); v0 += __shfl_down(v0, 4);
                    v0 += __shfl_down(v0, 2); v0 += __shfl_down(v0, 1);
                    v1 += __shfl_down(v1, 8); v1 += __shfl_down(v1, 4);
                    v1 += __shfl_down(v1, 2); v1 += __shfl_down(v1, 1);
                    if (hh == 0) {
                        atomicAdd(&out[(s - 7) * 1024 + 2 * i],     v0);
                        atomicAdd(&out[(s - 7) * 1024 + 2 * i + 1], v1);
                    }
                }
            }
            __syncthreads();
            if (t < 64) {   // coalesced bypass hs writeback: 64B per agent h-slice
                int rl = t >> 2, q = t & 3;
                vf4 v;
                v.x = hrow[rl * 16 + q * 4 + 0];
                v.y = hrow[rl * 16 + q * 4 + 1];
                v.z = hrow[rl * 16 + q * 4 + 2];
                v.w = hrow[rl * 16 + q * 4 + 3];
                st_bypass_f4(hs + (R0 + rl) * 128 + hc * 16 + q * 4, v);
            }
        }
        grid_barrier_nf(flags, gen, seq++);   // fence-free: weights stay cached
    }
}

extern "C" void kernel_launch(void* const* d_in, const int* in_sizes, int n_in,
                              void* d_out, int out_size, void* d_ws, size_t ws_size,
                              hipStream_t stream) {
    const float* observed = (const float*)d_in[0];
    const float* W_pos    = (const float*)d_in[1];
    const float* b_pos    = (const float*)d_in[2];
    const float* W_pool   = (const float*)d_in[3];
    const float* b_pool   = (const float*)d_in[4];
    const float* Wih_e    = (const float*)d_in[5];
    const float* bih_e    = (const float*)d_in[6];
    const float* Whh_e    = (const float*)d_in[7];
    const float* bhh_e    = (const float*)d_in[8];
    const float* Wih_d    = (const float*)d_in[9];
    const float* bih_d    = (const float*)d_in[10];
    const float* Whh_d    = (const float*)d_in[11];
    const float* bhh_d    = (const float*)d_in[12];
    const float* W_out    = (const float*)d_in[13];
    const float* b_out    = (const float*)d_in[14];
    float* outp = (float*)d_out;
    float* wsp  = (float*)d_ws;
    int npred = out_size / 1024;

    hipMemsetAsync(d_ws, 0, 33024, stream);   // arrival flags + gen + rt flags

    social_lstm<<<NBLK, NTHR, LDS_BYTES, stream>>>(
        observed, W_pos, b_pos, W_pool, b_pool,
        Wih_e, bih_e, Whh_e, bhh_e,
        Wih_d, bih_d, Whh_d, bhh_d,
        W_out, b_out, outp, wsp, npred);
}

// Round 14
// 606.485 us; speedup vs baseline: 2.2075x; 1.0562x over previous
//
#include <hip/hip_runtime.h>
#include <math.h>

#define NBLK 256
#define NTHR 512

// ---- ws layout ----
// uints: [b*16] arrival flags (b<256); [4096] gen; [4112 + (rt*8+kc)*16] rt-flags
// floats from 8256:
#define OFF_OBS     8256        // 8192    (cached, immutable after init barrier)
#define OFF_PART    16448       // 524288  (BYPASS domain: write+read-once, no reuse)
#define OFF_WTPOOL  540736      // 262144  (cached immutable)
#define OFF_WTG_E   802880      // 163840  (cached immutable)
#define OFF_WTG_D   966720      // 163840  (cached immutable)
#define OFF_HSBUF   1130560     // (nstep+1) * 65536 -- ROTATED hs buffers:
// hs[s+1] is written (bypass->MALL) in CD(s) and read CACHED in AB(s+1).
// Fresh addresses each step => no L2 line can be stale (write-once-then-read),
// so readers get full L2 caching of hs with ZERO fences. Cross-launch stale
// lines are killed by the init barrier's acquire-inv.
// total ~2.44M floats ~= 9.8 MB

#define LDS_BYTES 31232

typedef float vf4 __attribute__((ext_vector_type(4)));
typedef float vf2 __attribute__((ext_vector_type(2)));

// Swizzled AsT row offset: row*20 + 4-float pad every 32 rows (bank-tiling, r13).
__device__ __forceinline__ int asr20(int row) { return row * 20 + ((row >> 5) << 2); }

// ---------- L2-bypass (LLC-coherent) access ----------
__device__ __forceinline__ void st_bypass_f4(float* p, vf4 v) {
    asm volatile("global_store_dwordx4 %0, %1, off sc0 sc1" :: "v"(p), "v"(v) : "memory");
}
__device__ __forceinline__ void st_bypass_f2(float* p, vf2 v) {
    asm volatile("global_store_dwordx2 %0, %1, off sc0 sc1" :: "v"(p), "v"(v) : "memory");
}
__device__ __forceinline__ void ld_bypass_f4x8(const float* b, int stride, vf4* v) {
    asm volatile(
        "global_load_dwordx4 %0, %8, off sc0 sc1\n\t"
        "global_load_dwordx4 %1, %9, off sc0 sc1\n\t"
        "global_load_dwordx4 %2, %10, off sc0 sc1\n\t"
        "global_load_dwordx4 %3, %11, off sc0 sc1\n\t"
        "global_load_dwordx4 %4, %12, off sc0 sc1\n\t"
        "global_load_dwordx4 %5, %13, off sc0 sc1\n\t"
        "global_load_dwordx4 %6, %14, off sc0 sc1\n\t"
        "global_load_dwordx4 %7, %15, off sc0 sc1\n\t"
        "s_waitcnt vmcnt(0)"
        : "=&v"(v[0]), "=&v"(v[1]), "=&v"(v[2]), "=&v"(v[3]),
          "=&v"(v[4]), "=&v"(v[5]), "=&v"(v[6]), "=&v"(v[7])
        : "v"(b), "v"(b + stride), "v"(b + 2 * stride), "v"(b + 3 * stride),
          "v"(b + 4 * stride), "v"(b + 5 * stride), "v"(b + 6 * stride), "v"(b + 7 * stride)
        : "memory");
}

// Fenced barrier (init only).
__device__ __forceinline__ void grid_barrier_fenced(unsigned* flags, unsigned* gen, unsigned seq) {
    __syncthreads();
    if (threadIdx.x == 0)
        __builtin_amdgcn_fence(__ATOMIC_RELEASE, "agent");
    if (blockIdx.x == 0) {
        if (threadIdx.x < 64) {
            #pragma unroll
            for (int q = 0; q < 4; q++) {
                int bb = threadIdx.x * 4 + q;
                if (bb != 0) {
                    while (__hip_atomic_load(&flags[bb * 16], __ATOMIC_RELAXED,
                                             __HIP_MEMORY_SCOPE_AGENT) != seq)
                        __builtin_amdgcn_s_sleep(1);
                }
            }
        }
        __syncthreads();
        if (threadIdx.x == 0) {
            __hip_atomic_store(gen, seq, __ATOMIC_RELAXED, __HIP_MEMORY_SCOPE_AGENT);
            __builtin_amdgcn_fence(__ATOMIC_ACQUIRE, "agent");
        }
    } else {
        if (threadIdx.x == 0) {
            __hip_atomic_store(&flags[blockIdx.x * 16], seq, __ATOMIC_RELAXED,
                               __HIP_MEMORY_SCOPE_AGENT);
            while (__hip_atomic_load(gen, __ATOMIC_RELAXED,
                                     __HIP_MEMORY_SCOPE_AGENT) != seq)
                __builtin_amdgcn_s_sleep(2);
            __builtin_amdgcn_fence(__ATOMIC_ACQUIRE, "agent");
        }
    }
    __syncthreads();
}

// Fence-free steady-state barrier (cross-block mutable data is bypass or
// write-once-rotated -> no cache maintenance ever needed).
__device__ __forceinline__ void grid_barrier_nf(unsigned* flags, unsigned* gen, unsigned seq) {
    __syncthreads();
    if (blockIdx.x == 0) {
        if (threadIdx.x < 64) {
            #pragma unroll
            for (int q = 0; q < 4; q++) {
                int bb = threadIdx.x * 4 + q;
                if (bb != 0) {
                    while (__hip_atomic_load(&flags[bb * 16], __ATOMIC_RELAXED,
                                             __HIP_MEMORY_SCOPE_AGENT) != seq)
                        __builtin_amdgcn_s_sleep(1);
                }
            }
        }
        __syncthreads();
        if (threadIdx.x == 0)
            __hip_atomic_store(gen, seq, __ATOMIC_RELAXED, __HIP_MEMORY_SCOPE_AGENT);
    } else {
        if (threadIdx.x == 0) {
            __hip_atomic_store(&flags[blockIdx.x * 16], seq, __ATOMIC_RELAXED,
                               __HIP_MEMORY_SCOPE_AGENT);
            while (__hip_atomic_load(gen, __ATOMIC_RELAXED,
                                     __HIP_MEMORY_SCOPE_AGENT) != seq)
                __builtin_amdgcn_s_sleep(2);
        }
    }
    __syncthreads();
}

__device__ __forceinline__ float sigm(float x) { return 1.f / (1.f + expf(-x)); }

__global__ void __launch_bounds__(NTHR, 1) social_lstm(
    const float* __restrict__ observed,
    const float* __restrict__ W_pos, const float* __restrict__ b_pos,
    const float* __restrict__ W_pool, const float* __restrict__ b_pool,
    const float* __restrict__ Wih_e, const float* __restrict__ bih_e,
    const float* __restrict__ Whh_e, const float* __restrict__ bhh_e,
    const float* __restrict__ Wih_d, const float* __restrict__ bih_d,
    const float* __restrict__ Whh_d, const float* __restrict__ bhh_d,
    const float* __restrict__ W_out, const float* __restrict__ b_out,
    float* __restrict__ out, float* __restrict__ ws, int npred)
{
    extern __shared__ char smem_raw[];
    const int t = threadIdx.x, b = blockIdx.x;
    const int gid = b * NTHR + t;

    unsigned* flags  = (unsigned*)ws;
    unsigned* gen    = flags + 4096;
    unsigned* rtf    = flags + 4112;            // (rt*8+kc)*16
    float* obs     = ws + OFF_OBS;
    float* part    = ws + OFF_PART;
    float* Wt_pool = ws + OFF_WTPOOL;
    float* Wt_ge   = ws + OFF_WTG_E;
    float* Wt_gd   = ws + OFF_WTG_D;
    float* hsbuf   = ws + OFF_HSBUF;
    unsigned seq = 1;

    // ================= init =================
    if (gid < 65536) hsbuf[gid] = 0.f;          // hs[0] = 0 (cached; flushed at init barrier)
    if (gid < 512) {
        float vx[8], vy[8];
        int fin = 0;
        for (int tt = 0; tt < 8; tt++) {
            float x = observed[tt * 1024 + gid * 2];
            float y = observed[tt * 1024 + gid * 2 + 1];
            vx[tt] = x; vy[tt] = y;
            if (isfinite(x) && isfinite(y)) fin |= (1 << tt);
        }
        int firstv = -1;
        for (int tt = 7; tt >= 0; tt--) if (fin & (1 << tt)) firstv = tt;
        int last = -1;
        for (int tt = 0; tt < 8; tt++) {
            if (fin & (1 << tt)) last = tt;
            int take = (last >= 0) ? last : firstv;
            float ox = 0.f, oy = 0.f;
            if (take >= 0) { ox = vx[take]; oy = vy[take]; }
            obs[tt * 1024 + gid * 2]     = ox;
            obs[tt * 1024 + gid * 2 + 1] = oy;
        }
    }
    if (gid < 65536) {   // Wt_pool[k][p] = W_pool[p][k]
        int p = gid >> 9, k4 = gid & 511;
        float4 v = *(const float4*)(W_pool + p * 2048 + k4 * 4);
        float* dst = Wt_pool + (k4 * 4) * 128 + p;
        dst[0] = v.x; dst[128] = v.y; dst[256] = v.z; dst[384] = v.w;
    }
    for (int idx = gid; idx < 163840; idx += NBLK * NTHR) {
        int k = idx >> 9, o = idx & 511;
        float ve, vd;
        if (k < 192) { ve = Wih_e[o * 192 + k];       vd = Wih_d[o * 192 + k]; }
        else         { ve = Whh_e[o * 128 + k - 192]; vd = Whh_d[o * 128 + k - 192]; }
        Wt_ge[idx] = ve; Wt_gd[idx] = vd;
    }
    grid_barrier_fenced(flags, gen, seq++);   // one-time flush + invalidate

    const int rt = b >> 3, kc = b & 7, hc = kc;
    const int R0 = rt * 16;
    float cs_reg = 0.f;       // t<256: rl=t>>4, hh=t&15
    const int nstep = 7 + npred;

    for (int s = 0; s < nstep; s++) {
        const float* posp  = (s < 7) ? (obs + (s + 1) * 1024)
                                     : ((s == 7) ? (obs + 7 * 1024) : (out + (s - 8) * 1024));
        const float* prevp = (s < 7) ? (obs + s * 1024)
                                     : ((s <= 8) ? (obs + 7 * 1024) : (out + (s - 9) * 1024));
        const float* Wt_g = (s < 7) ? Wt_ge : Wt_gd;
        const float* bihp = (s < 7) ? bih_e : bih_d;
        const float* bhhp = (s < 7) ? bhh_e : bhh_d;
        const float* hs_r = hsbuf + s * 65536;        // read: CACHED (write-once addresses)
        float*       hs_w = hsbuf + (s + 1) * 65536;  // write: bypass -> MALL

        // ===== Phase AB: pooling (2 cells) + soc GEMM K-chunk =====
        {
            float* pos2 = (float*)smem_raw;                           // 1024 f
            int* cnt    = (int*)(smem_raw + 4096);                    // 32 i
            unsigned short* lst = (unsigned short*)(smem_raw + 4224); // 32*96 us
            float* AsT  = (float*)(smem_raw + 10368);                 // swizzled [256 rows][20]

            if (t < 256) ((float4*)pos2)[t] = ((const float4*)posp)[t];  // cached (out rows write-once)
            if (t < 32) cnt[t] = 0;
            __syncthreads();

            if (kc == 1 && s >= 7 && t < 16) {  // init out row = pos + b_out (bypass)
                int i = R0 + t;
                vf2 v;
                v.x = pos2[2 * i] + b_out[0];
                v.y = pos2[2 * i + 1] + b_out[1];
                st_bypass_f2(out + (s - 7) * 1024 + 2 * i, v);
            }
            {   // pair eval: agent a = t>>5, 32 threads/agent
                int a = t >> 5, i = R0 + a;
                float pix = pos2[2 * i], piy = pos2[2 * i + 1];
                int c0 = kc * 2;
                for (int jj = 0; jj < 16; jj++) {
                    int j = (t & 31) + jj * 32;
                    float dx = pos2[2 * j]     - pix;
                    float dy = pos2[2 * j + 1] - piy;
                    if (j != i && fabsf(dx) <= 1.0f && fabsf(dy) <= 1.0f) {
                        int gx = (int)floorf((dx + 1.0f) * 2.0f); gx = gx < 0 ? 0 : (gx > 3 ? 3 : gx);
                        int gy = (int)floorf((dy + 1.0f) * 2.0f); gy = gy < 0 ? 0 : (gy > 3 ? 3 : gy);
                        int cc = gx * 4 + gy - c0;
                        if (cc == 0 || cc == 1) {
                            int slot = atomicAdd(&cnt[a * 2 + cc], 1);
                            if (slot < 96) lst[(a * 2 + cc) * 96 + slot] = (unsigned short)j;
                        }
                    }
                }
            }
            __syncthreads();
            {   // cell max -> AsT[k][agent]: thread = (a, cc, hq); CACHED batched gather
                int a = t >> 5, cc = (t >> 4) & 1, hq = t & 15;
                int len = cnt[a * 2 + cc]; if (len > 96) len = 96;
                float m[8];
                #pragma unroll
                for (int u = 0; u < 8; u++) m[u] = -3.0e38f;
                const unsigned short* ll = lst + (a * 2 + cc) * 96;
                for (int e = 0; e < len; e += 8) {
                    float4 va[8], vb[8];
                    #pragma unroll
                    for (int k2 = 0; k2 < 8; k2++) {
                        int ee = e + k2; if (ee >= len) ee = len - 1;   // pad: max idempotent
                        const float4* hp = (const float4*)(hs_r + (int)ll[ee] * 128 + hq * 8);
                        va[k2] = hp[0]; vb[k2] = hp[1];
                    }
                    #pragma unroll
                    for (int k2 = 0; k2 < 8; k2++) {
                        m[0] = fmaxf(m[0], va[k2].x); m[1] = fmaxf(m[1], va[k2].y);
                        m[2] = fmaxf(m[2], va[k2].z); m[3] = fmaxf(m[3], va[k2].w);
                        m[4] = fmaxf(m[4], vb[k2].x); m[5] = fmaxf(m[5], vb[k2].y);
                        m[6] = fmaxf(m[6], vb[k2].z); m[7] = fmaxf(m[7], vb[k2].w);
                    }
                }
                #pragma unroll
                for (int u = 0; u < 8; u++)
                    AsT[asr20(cc * 128 + hq * 8 + u) + a] = (len > 0) ? m[u] : 0.f;
            }
            __syncthreads();
            {   // soc GEMM: 16r x 128o x K256; tile 4x8; in-wave 8-way ksplit
                int og = (t & 7) | (((t >> 6) & 1) << 3);
                int ks = (t >> 3) & 7;
                int rowg = t >> 7;
                float acc[4][8];
                #pragma unroll
                for (int r = 0; r < 4; r++)
                    #pragma unroll
                    for (int o = 0; o < 8; o++) acc[r][o] = 0.f;
                const float4* W4 = (const float4*)Wt_pool;   // L2-resident all steps
                int kb = kc * 256 + ks * 32;
                #pragma unroll 4
                for (int kk = 0; kk < 32; kk++) {
                    int kl = ks * 32 + kk;
                    float4 a4 = *(const float4*)&AsT[asr20(kl) + rowg * 4];
                    float4 w0 = W4[(kb + kk) * 32 + og * 2];
                    float4 w1 = W4[(kb + kk) * 32 + og * 2 + 1];
                    float ar[4] = {a4.x, a4.y, a4.z, a4.w};
                    float wo[8] = {w0.x, w0.y, w0.z, w0.w, w1.x, w1.y, w1.z, w1.w};
                    #pragma unroll
                    for (int r = 0; r < 4; r++)
                        #pragma unroll
                        for (int o = 0; o < 8; o++)
                            acc[r][o] = fmaf(ar[r], wo[o], acc[r][o]);
                }
                #pragma unroll
                for (int r = 0; r < 4; r++)
                    #pragma unroll
                    for (int o = 0; o < 8; o++) {
                        acc[r][o] += __shfl_xor(acc[r][o], 8);
                        acc[r][o] += __shfl_xor(acc[r][o], 16);
                        acc[r][o] += __shfl_xor(acc[r][o], 32);
                    }
                if ((t & 56) == 0) {
                    #pragma unroll
                    for (int r = 0; r < 4; r++) {
                        int row = R0 + rowg * 4 + r;
                        float* pp = part + kc * 65536 + row * 128 + og * 8;
                        vf4 lo, hi;
                        lo.x = acc[r][0]; lo.y = acc[r][1]; lo.z = acc[r][2]; lo.w = acc[r][3];
                        hi.x = acc[r][4]; hi.y = acc[r][5]; hi.z = acc[r][6]; hi.w = acc[r][7];
                        st_bypass_f4(pp,     lo);
                        st_bypass_f4(pp + 4, hi);
                    }
                }
            }
        }

        // ===== rt-sync (parallel flags) overlapped with CD staging =====
        __syncthreads();                 // drains this block's bypass stores (vmcnt)
        if (t == 0)
            __hip_atomic_store(&rtf[(rt * 8 + kc) * 16], (unsigned)(s + 1),
                               __ATOMIC_RELAXED, __HIP_MEMORY_SCOPE_AGENT);
        {
            float* AsT  = (float*)smem_raw;                 // swizzled [320 rows][20]
            {   // stage emb rows (k 0..63): independent of part -> do before poll
                int r = t >> 5, e2 = (t & 31) * 2;
                int i2 = 2 * (R0 + r);
                float vx = posp[i2]     - prevp[i2];
                float vy = posp[i2 + 1] - prevp[i2 + 1];
                float e0 = fmaxf(W_pos[e2 * 2]     * vx + W_pos[e2 * 2 + 1] * vy + b_pos[e2],     0.f);
                float e1 = fmaxf(W_pos[e2 * 2 + 2] * vx + W_pos[e2 * 2 + 3] * vy + b_pos[e2 + 1], 0.f);
                AsT[asr20(e2 + 0) + r] = e0;
                AsT[asr20(e2 + 1) + r] = e1;
            }
            {   // stage hs rows (k 192..319): cached (L2-hot from gather)
                int r = t >> 5, h4 = (t & 31) * 4;
                float4 v = *(const float4*)(hs_r + (R0 + r) * 128 + h4);
                AsT[asr20(192 + h4 + 0) + r] = v.x;
                AsT[asr20(192 + h4 + 1) + r] = v.y;
                AsT[asr20(192 + h4 + 2) + r] = v.z;
                AsT[asr20(192 + h4 + 3) + r] = v.w;
            }
            // poll the 8 producer flags in parallel
            if (t < 8) {
                while (__hip_atomic_load(&rtf[(rt * 8 + t) * 16], __ATOMIC_RELAXED,
                                         __HIP_MEMORY_SCOPE_AGENT) != (unsigned)(s + 1))
                    __builtin_amdgcn_s_sleep(1);
            }
            __syncthreads();
            {   // stage soc rows (k 64..191): bypass part reduce + bias + relu
                int r = t >> 5, p4 = (t & 31) * 4;
                vf4 pv[8];
                ld_bypass_f4x8(part + (R0 + r) * 128 + p4, 65536, pv);
                float sv[4] = {0.f, 0.f, 0.f, 0.f};
                #pragma unroll
                for (int kc2 = 0; kc2 < 8; kc2++) {
                    sv[0] += pv[kc2].x; sv[1] += pv[kc2].y;
                    sv[2] += pv[kc2].z; sv[3] += pv[kc2].w;
                }
                #pragma unroll
                for (int u = 0; u < 4; u++)
                    AsT[asr20(64 + p4 + u) + r] = fmaxf(sv[u] + b_pool[p4 + u], 0.f);
            }
            __syncthreads();
            float* red  = (float*)(smem_raw + 25792);       // [16][64]
            float* hrow = (float*)(smem_raw + 29888);       // [16][16]
            {   // gates GEMM: 16r x 64o x K320; tile 4x4; in-wave 8-way ksplit
                int og = (t & 7) | (((t >> 6) & 1) << 3);
                int ks = (t >> 3) & 7;
                int rowg = t >> 7;
                int col4 = (og >> 2) * 32 + hc * 4 + (og & 3);
                float acc[4][4];
                #pragma unroll
                for (int r = 0; r < 4; r++)
                    #pragma unroll
                    for (int o = 0; o < 4; o++) acc[r][o] = 0.f;
                const float4* Wg4 = (const float4*)Wt_g;    // L2-resident
                #pragma unroll 4
                for (int kk = 0; kk < 40; kk++) {
                    int k = ks * 40 + kk;
                    float4 a4 = *(const float4*)&AsT[asr20(k) + rowg * 4];
                    float4 w  = Wg4[k * 128 + col4];
                    float ar[4] = {a4.x, a4.y, a4.z, a4.w};
                    float wo[4] = {w.x, w.y, w.z, w.w};
                    #pragma unroll
                    for (int r = 0; r < 4; r++)
                        #pragma unroll
                        for (int o = 0; o < 4; o++)
                            acc[r][o] = fmaf(ar[r], wo[o], acc[r][o]);
                }
                #pragma unroll
                for (int r = 0; r < 4; r++)
                    #pragma unroll
                    for (int o = 0; o < 4; o++) {
                        acc[r][o] += __shfl_xor(acc[r][o], 8);
                        acc[r][o] += __shfl_xor(acc[r][o], 16);
                        acc[r][o] += __shfl_xor(acc[r][o], 32);
                    }
                if ((t & 56) == 0) {
                    #pragma unroll
                    for (int r = 0; r < 4; r++)
                        *(float4*)&red[(rowg * 4 + r) * 64 + og * 4] =
                            make_float4(acc[r][0], acc[r][1], acc[r][2], acc[r][3]);
                }
            }
            __syncthreads();
            if (t < 256) {   // pointwise LSTM
                int rl = t >> 4, hh = t & 15;
                float g4[4];
                #pragma unroll
                for (int q = 0; q < 4; q++) {
                    int colq = q * 128 + hc * 16 + hh;
                    g4[q] = red[rl * 64 + q * 16 + hh] + bihp[colq] + bhhp[colq];
                }
                float si = sigm(g4[0]);
                float sf = sigm(g4[1]);
                float so = sigm(g4[3]);
                float c2 = sf * cs_reg + si * tanhf(g4[2]);
                float h2 = so * tanhf(c2);
                cs_reg = c2;
                hrow[rl * 16 + hh] = h2;
                if (s >= 7) {
                    int i = R0 + rl, h = hc * 16 + hh;
                    float v0 = W_out[h] * h2;
                    float v1 = W_out[128 + h] * h2;
                    v0 += __shfl_down(v0, 8); v0 += __shfl_down(v0, 4);
                    v0 += __shfl_down(v0, 2); v0 += __shfl_down(v0, 1);
                    v1 += __shfl_down(v1, 8); v1 += __shfl_down(v1, 4);
                    v1 += __shfl_down(v1, 2); v1 += __shfl_down(v1, 1);
                    if (hh == 0) {
                        atomicAdd(&out[(s - 7) * 1024 + 2 * i],     v0);
                        atomicAdd(&out[(s - 7) * 1024 + 2 * i + 1], v1);
                    }
                }
            }
            __syncthreads();
            if (t < 64) {   // bypass hs writeback into NEXT rotated buffer (-> MALL)
                int rl = t >> 2, q = t & 3;
                vf4 v;
                v.x = hrow[rl * 16 + q * 4 + 0];
                v.y = hrow[rl * 16 + q * 4 + 1];
                v.z = hrow[rl * 16 + q * 4 + 2];
                v.w = hrow[rl * 16 + q * 4 + 3];
                st_bypass_f4(hs_w + (R0 + rl) * 128 + hc * 16 + q * 4, v);
            }
        }
        grid_barrier_nf(flags, gen, seq++);   // fence-free
    }
}

extern "C" void kernel_launch(void* const* d_in, const int* in_sizes, int n_in,
                              void* d_out, int out_size, void* d_ws, size_t ws_size,
                              hipStream_t stream) {
    const float* observed = (const float*)d_in[0];
    const float* W_pos    = (const float*)d_in[1];
    const float* b_pos    = (const float*)d_in[2];
    const float* W_pool   = (const float*)d_in[3];
    const float* b_pool   = (const float*)d_in[4];
    const float* Wih_e    = (const float*)d_in[5];
    const float* bih_e    = (const float*)d_in[6];
    const float* Whh_e    = (const float*)d_in[7];
    const float* bhh_e    = (const float*)d_in[8];
    const float* Wih_d    = (const float*)d_in[9];
    const float* bih_d    = (const float*)d_in[10];
    const float* Whh_d    = (const float*)d_in[11];
    const float* bhh_d    = (const float*)d_in[12];
    const float* W_out    = (const float*)d_in[13];
    const float* b_out    = (const float*)d_in[14];
    float* outp = (float*)d_out;
    float* wsp  = (float*)d_ws;
    int npred = out_size / 1024;

    hipMemsetAsync(d_ws, 0, 33024, stream);   // arrival flags + gen + rt flags

    social_lstm<<<NBLK, NTHR, LDS_BYTES, stream>>>(
        observed, W_pos, b_pos, W_pool, b_pool,
        Wih_e, bih_e, Whh_e, bhh_e,
        Wih_d, bih_d, Whh_d, bhh_d,
        W_out, b_out, outp, wsp, npred);
}